// Round 4
// baseline (518.756 us; speedup 1.0000x reference)
//
#include <hip/hip_runtime.h>
#include <cstdint>
#include <cstddef>

#define BN_EPS 1e-5f

typedef __attribute__((ext_vector_type(8))) short short8v;
typedef __attribute__((ext_vector_type(4))) float float4v;
typedef __attribute__((ext_vector_type(4))) unsigned int uint4v;
typedef unsigned int uint32;
typedef unsigned short ushort16;

__device__ __forceinline__ float elu_f(float v){ return v > 0.f ? v : expm1f(v); }
__device__ __forceinline__ float leaky_f(float v){ return v > 0.f ? v : 0.2f*v; }
__device__ __forceinline__ uint32 f2bf(float f){
  uint32 b = __float_as_uint(f);
  return (b + 0x7fffu + ((b >> 16) & 1u)) >> 16;        // RNE
}
__device__ __forceinline__ float bflo(uint32 u){ return __uint_as_float(u << 16); }
__device__ __forceinline__ float bfhi(uint32 u){ return __uint_as_float(u & 0xffff0000u); }

// ---------------- graph preprocessing: CSR by dst ----------------

__global__ void count_deg_kernel(const int* __restrict__ dst, int E, int* __restrict__ cnt){
  int i = blockIdx.x*blockDim.x + threadIdx.x;
  if(i < E) atomicAdd(&cnt[dst[i]], 1);
}

// phase 1: per-block (1024-wide) exclusive scan + block sums
__global__ __launch_bounds__(1024) void scan_blocks(const int* __restrict__ cnt, int n,
                                                    int* __restrict__ part, int* __restrict__ bsum){
  __shared__ int wsum[16];
  int tid = threadIdx.x, lane = tid & 63, w = tid >> 6;
  int i = blockIdx.x*1024 + tid;
  int v = (i < n) ? cnt[i] : 0;
  int sv = v;
#pragma unroll
  for(int o = 1; o < 64; o <<= 1){
    int u = __shfl_up(sv, o);
    if(lane >= o) sv += u;
  }
  if(lane == 63) wsum[w] = sv;
  __syncthreads();
  int woff = 0;
#pragma unroll
  for(int q = 0; q < 16; q++) woff += (q < w) ? wsum[q] : 0;
  if(i < n) part[i] = woff + sv - v;          // exclusive within block
  if(tid == 1023) bsum[blockIdx.x] = woff + sv;  // block total
}

// phase 2: single block scans block sums (nb <= 1024), writes rowptr[n] = total
__global__ __launch_bounds__(1024) void scan_bsum(const int* __restrict__ bsum, int nb,
                                                  int* __restrict__ boff, int* __restrict__ rowptr, int n){
  __shared__ int wsum[16];
  int tid = threadIdx.x, lane = tid & 63, w = tid >> 6;
  int v = (tid < nb) ? bsum[tid] : 0;
  int sv = v;
#pragma unroll
  for(int o = 1; o < 64; o <<= 1){
    int u = __shfl_up(sv, o);
    if(lane >= o) sv += u;
  }
  if(lane == 63) wsum[w] = sv;
  __syncthreads();
  int woff = 0;
#pragma unroll
  for(int q = 0; q < 16; q++) woff += (q < w) ? wsum[q] : 0;
  if(tid < nb) boff[tid] = woff + sv - v;
  if(tid == 1023) rowptr[n] = woff + sv;
}

// phase 3: assemble rowptr; fused dinv
__global__ void scan_add_dinv(const int* __restrict__ part, const int* __restrict__ boff,
                              const int* __restrict__ cnt, int n,
                              int* __restrict__ rowptr, float* __restrict__ dinv){
  int i = blockIdx.x*blockDim.x + threadIdx.x;
  if(i < n){
    rowptr[i] = part[i] + boff[i >> 10];
    dinv[i] = rsqrtf((float)cnt[i] + 1.0f);   // deg includes self loop
  }
}

__global__ void scatter_kernel(const int* __restrict__ src, const int* __restrict__ dst, int E,
                               const int* __restrict__ rowptr, int* __restrict__ fill, int* __restrict__ col){
  int i = blockIdx.x*blockDim.x + threadIdx.x;
  if(i < E){
    int d = dst[i];
    int pos = rowptr[d] + atomicAdd(&fill[d], 1);
    col[pos] = src[i];
  }
}

// ---------------- x -> bf16, K padded 165 -> 192, packed uint writes ----------------

__global__ __launch_bounds__(256) void cvt_x(const float* __restrict__ x, uint32* __restrict__ xb, int total){
  int idx = blockIdx.x*256 + threadIdx.x;     // over N*96 packed uints
  if(idx >= total) return;
  int row = idx/96;
  int cp = idx - row*96;
  int c = cp*2;
  const float* xr = x + (size_t)row*165;
  float v0 = (c < 165) ? xr[c] : 0.f;
  float v1 = (c < 164) ? xr[c+1] : 0.f;
  xb[idx] = f2bf(v0) | (f2bf(v1) << 16);
}

// ---------------- weight packing (one launch): packed[kgrp][col][8] bf16 ----------------

__device__ __forceinline__ void pack_region(const float* __restrict__ W, int K, int NOUT, int kbase, int idx,
                                            const float* __restrict__ scale, ushort16* __restrict__ out){
  int k = idx / NOUT, c = idx - k*NOUT;
  float v = (k < K) ? W[(size_t)k*NOUT + c] : 0.f;
  if(scale) v *= scale[c];
  int pk = kbase + k;
  out[(size_t)(pk >> 3)*NOUT*8 + (size_t)c*8 + (pk & 7)] = (ushort16)f2bf(v);
}

__global__ __launch_bounds__(256) void pack_all(const float* __restrict__ w_in, const float* __restrict__ w_gcn,
    const float* __restrict__ w_gat, const float* __restrict__ w_sl, const float* __restrict__ w_sr,
    const float* __restrict__ w_res, const float* __restrict__ s3,
    ushort16* __restrict__ pw_in, ushort16* __restrict__ pw_gcn,
    ushort16* __restrict__ pw_gat, ushort16* __restrict__ pw_cat){
  int b = blockIdx.x, t = threadIdx.x;
  if(b < 96)       pack_region(w_in,  165, 128, 0,   b*256 + t,        nullptr, pw_in);
  else if(b < 160) pack_region(w_gcn, 128, 128, 0,   (b-96)*256 + t,   nullptr, pw_gcn);
  else if(b < 224) pack_region(w_gat, 128, 128, 0,   (b-160)*256 + t,  nullptr, pw_gat);
  else if(b < 256) pack_region(w_sl,  128, 64,  0,   (b-224)*256 + t,  s3,      pw_cat);
  else if(b < 288) pack_region(w_sr,  128, 64,  128, (b-256)*256 + t,  s3,      pw_cat);
  else             pack_region(w_res, 128, 64,  256, (b-288)*256 + t,  nullptr, pw_cat);
}

// bn3 scale + combined bias for the fused SAGE epilogue
__global__ void prep3(const float* __restrict__ bg, const float* __restrict__ bb,
                      const float* __restrict__ bm, const float* __restrict__ bv,
                      const float* __restrict__ b_sage, const float* __restrict__ b_res,
                      float* __restrict__ s3, float* __restrict__ bias3){
  int c = threadIdx.x;   // 64
  float s = bg[c]*rsqrtf(bv[c] + BN_EPS);
  s3[c] = s;
  bias3[c] = (b_sage[c] - bm[c])*s + bb[c] + b_res[c];
}

// ---------------- MFMA bf16 GEMM ----------------
// out[M x NOUT] = epi(A[M x K] @ W)   A bf16 row-major (lda elements), W packed in global.
// EPI: 0 = raw -> bf16, 1 = bias+elu -> bf16, 2 = bias+elu -> fp32
// NOUT=128: 4 waves 2x2, tile 128x128. NOUT=64: 4 waves 4x1, tile 256x64.

template<int KSTEPS, int NOUT, int EPI>
__global__ __launch_bounds__(256) void mfma_gemm(
    const ushort16* __restrict__ A, int lda,
    const uint4v* __restrict__ pw,
    const float* __restrict__ bias,
    void* __restrict__ out, int ldo, int N)
{
  constexpr int LDSV = KSTEPS*4*NOUT;         // uint4 entries (16 B each)
  __shared__ uint4v wlds[LDSV];
  int t = threadIdx.x;
#pragma unroll
  for(int q = 0; q < LDSV/256; q++)
    wlds[q*256 + t] = pw[q*256 + t];
  __syncthreads();

  int wid = t >> 6, lane = t & 63;
  int wm, wn;
  if(NOUT == 128){ wm = wid >> 1; wn = wid & 1; } else { wm = wid; wn = 0; }
  constexpr int MTILE = (NOUT == 128) ? 128 : 256;
  long row0 = (long)blockIdx.x*MTILE + wm*64;
  int l15 = lane & 15, lk = lane >> 4;
  int wn64 = wn*64;
  const ushort16* wl = (const ushort16*)wlds;

  float4v acc[4][4];
#pragma unroll
  for(int fm = 0; fm < 4; fm++)
#pragma unroll
    for(int fn = 0; fn < 4; fn++) acc[fm][fn] = (float4v){0.f,0.f,0.f,0.f};

  const ushort16* abase[4];
#pragma unroll
  for(int fm = 0; fm < 4; fm++){
    long r = row0 + fm*16 + l15;
    if(r > (long)N - 1) r = (long)N - 1;
    abase[fm] = A + r*(size_t)lda + lk*8;
  }

  short8v a[4];
#pragma unroll
  for(int fm = 0; fm < 4; fm++) a[fm] = *(const short8v*)(abase[fm]);

#pragma unroll
  for(int ks = 0; ks < KSTEPS; ks++){
    short8v b[4];
#pragma unroll
    for(int fn = 0; fn < 4; fn++){
      int c = wn64 + fn*16 + l15;
      b[fn] = *(const short8v*)(wl + ((size_t)((ks*4 + lk)*NOUT + c))*8);
    }
    short8v an[4];
    if(ks + 1 < KSTEPS){
#pragma unroll
      for(int fm = 0; fm < 4; fm++) an[fm] = *(const short8v*)(abase[fm] + (ks + 1)*32);
    }
#pragma unroll
    for(int fm = 0; fm < 4; fm++)
#pragma unroll
      for(int fn = 0; fn < 4; fn++)
        acc[fm][fn] = __builtin_amdgcn_mfma_f32_16x16x32_bf16(a[fm], b[fn], acc[fm][fn], 0, 0, 0);
    if(ks + 1 < KSTEPS){
#pragma unroll
      for(int fm = 0; fm < 4; fm++) a[fm] = an[fm];
    }
  }

  // C/D layout: col = lane&15, row = (lane>>4)*4 + reg  [m89 verified]
#pragma unroll
  for(int fm = 0; fm < 4; fm++){
#pragma unroll
    for(int rr = 0; rr < 4; rr++){
      long r = row0 + fm*16 + lk*4 + rr;
      if(r < N){
#pragma unroll
        for(int fn = 0; fn < 4; fn++){
          int c = wn64 + fn*16 + l15;
          float v = acc[fm][fn][rr];
          if constexpr(EPI >= 1){ v += bias[c]; v = elu_f(v); }
          if constexpr(EPI == 2) ((float*)out)[r*(size_t)ldo + c] = v;
          else ((ushort16*)out)[r*(size_t)ldo + c] = (ushort16)f2bf(v);
        }
      }
    }
  }
}

// ---------------- GCN aggregation + BN1 + ELU (dwordx4 gathers, 4 rows/iter) ----------------

__global__ __launch_bounds__(64) void gcn_agg(const uint32* __restrict__ hw,   // stride 64 uints (256 B)
    const int* __restrict__ rowptr, const int* __restrict__ col, const float* __restrict__ dinv,
    const float* __restrict__ b, const float* __restrict__ bg, const float* __restrict__ bb,
    const float* __restrict__ bm, const float* __restrict__ bv,
    uint32* __restrict__ h1, int N)
{
  __shared__ int sbuf[64];
  __shared__ float dbuf[64];
  int i = blockIdx.x, t = threadIdx.x;
  int lane16 = t & 15, grp = t >> 4;
  const char* hwb = (const char*)hw;
  float di = dinv[i];
  int beg = rowptr[i], end = rowptr[i+1];
  float acc[8];
#pragma unroll
  for(int j = 0; j < 8; j++) acc[j] = 0.f;

  for(int c0 = beg; c0 < end; c0 += 64){
    int p = c0 + t;
    int s = 0; float ds = 0.f;
    if(p < end){ s = col[p]; ds = dinv[s]; }
    sbuf[t] = s; dbuf[t] = ds;
    __syncthreads();
    int cl = min(64, end - c0);
    for(int q = grp; q < cl; q += 4){
      float w = dbuf[q];
      uint4v v = *(const uint4v*)(hwb + (size_t)sbuf[q]*256 + lane16*16);
#pragma unroll
      for(int j = 0; j < 4; j++){
        acc[2*j]   += w*bflo(v[j]);
        acc[2*j+1] += w*bfhi(v[j]);
      }
    }
    __syncthreads();
  }
#pragma unroll
  for(int j = 0; j < 8; j++){
    acc[j] += __shfl_xor(acc[j], 16);
    acc[j] += __shfl_xor(acc[j], 32);
  }
  if(grp == 0){
    uint4v sv = *(const uint4v*)(hwb + (size_t)i*256 + lane16*16);
    uint4v ov;
#pragma unroll
    for(int j = 0; j < 4; j++){
      int c0i = lane16*8 + 2*j, c1i = c0i + 1;
      float v0 = (acc[2*j]   + bflo(sv[j])*di)*di + b[c0i];
      float v1 = (acc[2*j+1] + bfhi(sv[j])*di)*di + b[c1i];
      v0 = elu_f((v0 - bm[c0i])*(bg[c0i]*rsqrtf(bv[c0i] + BN_EPS)) + bb[c0i]);
      v1 = elu_f((v1 - bm[c1i])*(bg[c1i]*rsqrtf(bv[c1i] + BN_EPS)) + bb[c1i]);
      ov[j] = f2bf(v0) | (f2bf(v1) << 16);
    }
    *(uint4v*)((char*)h1 + (size_t)i*256 + lane16*16) = ov;
  }
}

// ---------------- GAT attention scalars (4 nodes/block, dwordx4) ----------------

__global__ __launch_bounds__(64) void att_kernel(const uint32* __restrict__ g,
    const float* __restrict__ att_s, const float* __restrict__ att_d,
    float* __restrict__ a_src, float* __restrict__ a_dst, int N)
{
  __shared__ float asl[128], adl[128];
  int t = threadIdx.x;
  ((float2*)asl)[t] = ((const float2*)att_s)[t];
  ((float2*)adl)[t] = ((const float2*)att_d)[t];
  __syncthreads();
  int lane16 = t & 15, grp = t >> 4;
  int i = blockIdx.x*4 + grp;
  if(i >= N) return;
  uint4v v = *(const uint4v*)((const char*)g + (size_t)i*256 + lane16*16);
  float s1 = 0.f, s2 = 0.f;
#pragma unroll
  for(int j = 0; j < 4; j++){
    int c0 = lane16*8 + 2*j;
    float g0 = bflo(v[j]), g1 = bfhi(v[j]);
    s1 += g0*asl[c0] + g1*asl[c0+1];
    s2 += g0*adl[c0] + g1*adl[c0+1];
  }
#pragma unroll
  for(int o = 1; o < 8; o <<= 1){ s1 += __shfl_xor(s1, o); s2 += __shfl_xor(s2, o); }
  if((lane16 & 7) == 0){
    int h = lane16 >> 3;
    a_src[2*i + h] = s1; a_dst[2*i + h] = s2;
  }
}

// ---------------- GAT softmax + weighted agg + BN2 + ELU (dwordx4 gathers) ----------------
// writes h2 (bf16) into Acat[:,128:256]  (out pre-offset, stride 192 uints = 768 B)

__global__ __launch_bounds__(64) void gat_agg(const uint32* __restrict__ g,   // stride 64 uints
    const float* __restrict__ a_src, const float* __restrict__ a_dst,
    const int* __restrict__ rowptr, const int* __restrict__ col,
    const float* __restrict__ b_gat, const float* __restrict__ bg, const float* __restrict__ bb,
    const float* __restrict__ bm, const float* __restrict__ bv,
    uint32* __restrict__ h2out, int N)
{
  __shared__ int sbuf[64];
  __shared__ float w0buf[64], w1buf[64];
  int i = blockIdx.x, t = threadIdx.x;
  int lane16 = t & 15, grp = t >> 4;
  int hl = lane16 >> 3;                     // head owning this lane's channels
  const char* gb = (const char*)g;
  int beg = rowptr[i], end = rowptr[i+1];
  int deg = end - beg;
  float2 ad  = ((const float2*)a_dst)[i];
  float2 asv = ((const float2*)a_src)[i];
  float es0 = leaky_f(asv.x + ad.x), es1 = leaky_f(asv.y + ad.y);
  float acc[8];
#pragma unroll
  for(int j = 0; j < 8; j++) acc[j] = 0.f;
  float D0, D1, M0, M1;
  const float* wb = hl ? w1buf : w0buf;

  if(deg <= 64){
    // ---- fast path: one exp per edge per head, weights staged in LDS ----
    float l0 = -1e30f, l1 = -1e30f;
    if(t < deg){
      int s = col[beg + t];
      sbuf[t] = s;
      float2 a = ((const float2*)a_src)[s];
      l0 = leaky_f(a.x + ad.x); l1 = leaky_f(a.y + ad.y);
    }
    float m0 = fmaxf(l0, es0), m1 = fmaxf(l1, es1);
#pragma unroll
    for(int o = 32; o > 0; o >>= 1){ m0 = fmaxf(m0, __shfl_xor(m0, o)); m1 = fmaxf(m1, __shfl_xor(m1, o)); }
    float e0 = (t < deg) ? __expf(l0 - m0) : 0.f;
    float e1 = (t < deg) ? __expf(l1 - m1) : 0.f;
    w0buf[t] = e0; w1buf[t] = e1;
    float d0 = e0, d1 = e1;
#pragma unroll
    for(int o = 32; o > 0; o >>= 1){ d0 += __shfl_xor(d0, o); d1 += __shfl_xor(d1, o); }
    D0 = d0 + __expf(es0 - m0) + 1e-16f;
    D1 = d1 + __expf(es1 - m1) + 1e-16f;
    M0 = m0; M1 = m1;
    __syncthreads();
    for(int q = grp; q < deg; q += 4){
      float w = wb[q];
      uint4v v = *(const uint4v*)(gb + (size_t)sbuf[q]*256 + lane16*16);
#pragma unroll
      for(int j = 0; j < 4; j++){
        acc[2*j]   += w*bflo(v[j]);
        acc[2*j+1] += w*bfhi(v[j]);
      }
    }
  } else {
    // ---- generic path (deg > 64) ----
    float m0 = es0, m1 = es1;
    for(int p = beg + t; p < end; p += 64){
      float2 a = ((const float2*)a_src)[col[p]];
      m0 = fmaxf(m0, leaky_f(a.x + ad.x));
      m1 = fmaxf(m1, leaky_f(a.y + ad.y));
    }
#pragma unroll
    for(int o = 32; o > 0; o >>= 1){ m0 = fmaxf(m0, __shfl_xor(m0, o)); m1 = fmaxf(m1, __shfl_xor(m1, o)); }
    float d0 = 0.f, d1 = 0.f;
    for(int c0 = beg; c0 < end; c0 += 64){
      int p = c0 + t;
      float e0 = 0.f, e1 = 0.f;
      int s = 0;
      if(p < end){
        s = col[p];
        float2 a = ((const float2*)a_src)[s];
        e0 = __expf(leaky_f(a.x + ad.x) - m0);
        e1 = __expf(leaky_f(a.y + ad.y) - m1);
      }
      d0 += e0; d1 += e1;
      sbuf[t] = s; w0buf[t] = e0; w1buf[t] = e1;
      __syncthreads();
      int cl = min(64, end - c0);
      for(int q = grp; q < cl; q += 4){
        float w = wb[q];
        uint4v v = *(const uint4v*)(gb + (size_t)sbuf[q]*256 + lane16*16);
#pragma unroll
        for(int j = 0; j < 4; j++){
          acc[2*j]   += w*bflo(v[j]);
          acc[2*j+1] += w*bfhi(v[j]);
        }
      }
      __syncthreads();
    }
#pragma unroll
    for(int o = 32; o > 0; o >>= 1){ d0 += __shfl_xor(d0, o); d1 += __shfl_xor(d1, o); }
    D0 = d0 + __expf(es0 - m0) + 1e-16f;
    D1 = d1 + __expf(es1 - m1) + 1e-16f;
    M0 = m0; M1 = m1;
  }

#pragma unroll
  for(int j = 0; j < 8; j++){
    acc[j] += __shfl_xor(acc[j], 16);
    acc[j] += __shfl_xor(acc[j], 32);
  }
  if(grp == 0){
    float Mh = hl ? M1 : M0;
    float rD = 1.f/(hl ? D1 : D0);
    float ws = __expf((hl ? es1 : es0) - Mh);
    uint4v sv = *(const uint4v*)(gb + (size_t)i*256 + lane16*16);
    uint4v ov;
#pragma unroll
    for(int j = 0; j < 4; j++){
      int c0i = lane16*8 + 2*j, c1i = c0i + 1;
      float v0 = (acc[2*j]   + ws*bflo(sv[j]))*rD + b_gat[c0i];
      float v1 = (acc[2*j+1] + ws*bfhi(sv[j]))*rD + b_gat[c1i];
      v0 = elu_f((v0 - bm[c0i])*(bg[c0i]*rsqrtf(bv[c0i] + BN_EPS)) + bb[c0i]);
      v1 = elu_f((v1 - bm[c1i])*(bg[c1i]*rsqrtf(bv[c1i] + BN_EPS)) + bb[c1i]);
      ov[j] = f2bf(v0) | (f2bf(v1) << 16);
    }
    *(uint4v*)((char*)h2out + (size_t)i*768 + lane16*16) = ov;
  }
}

// ---------------- SAGE mean (no self loops), dwordx4 gathers, inside Acat ----------------

__global__ __launch_bounds__(64) void sage_mean(const uint32* __restrict__ h2,  // pre-offset +64, stride 192
    const int* __restrict__ rowptr, const int* __restrict__ col,
    uint32* __restrict__ mout, int N)                                            // stride 192
{
  __shared__ int sbuf[64];
  int i = blockIdx.x, t = threadIdx.x;
  int lane16 = t & 15, grp = t >> 4;
  const char* hb = (const char*)h2;
  int beg = rowptr[i], end = rowptr[i+1];
  float acc[8];
#pragma unroll
  for(int j = 0; j < 8; j++) acc[j] = 0.f;
  for(int c0 = beg; c0 < end; c0 += 64){
    int p = c0 + t;
    sbuf[t] = (p < end) ? col[p] : 0;
    __syncthreads();
    int cl = min(64, end - c0);
    for(int q = grp; q < cl; q += 4){
      uint4v v = *(const uint4v*)(hb + (size_t)sbuf[q]*768 + lane16*16);
#pragma unroll
      for(int j = 0; j < 4; j++){
        acc[2*j]   += bflo(v[j]);
        acc[2*j+1] += bfhi(v[j]);
      }
    }
    __syncthreads();
  }
#pragma unroll
  for(int j = 0; j < 8; j++){
    acc[j] += __shfl_xor(acc[j], 16);
    acc[j] += __shfl_xor(acc[j], 32);
  }
  if(grp == 0){
    float inv = 1.f/fmaxf((float)(end - beg), 1.f);
    uint4v ov;
#pragma unroll
    for(int j = 0; j < 4; j++)
      ov[j] = f2bf(acc[2*j]*inv) | (f2bf(acc[2*j+1]*inv) << 16);
    *(uint4v*)((char*)mout + (size_t)i*768 + lane16*16) = ov;
  }
}

// ---------------- classifier: out = elu(h3@w1+b1)@w2 + b2 ----------------

__global__ __launch_bounds__(256) void classifier_kernel(const float* __restrict__ h3,
    const float* __restrict__ w1, const float* __restrict__ b1,
    const float* __restrict__ w2, const float* __restrict__ b2,
    float* __restrict__ out, int N)
{
  __shared__ float hs[8][64];
  __shared__ float zs[8][32];
  int node0 = blockIdx.x*8;
  int t = threadIdx.x;
#pragma unroll
  for(int q = 0; q < 2; q++){
    int e = t + q*256;
    int r = e >> 6, c = e & 63;
    int nd = node0 + r;
    hs[r][c] = (nd < N) ? h3[(size_t)nd*64 + c] : 0.f;
  }
  __syncthreads();
  int nn = t >> 5, ln = t & 31;
  float acc = b1[ln];
#pragma unroll
  for(int k = 0; k < 64; k++) acc += hs[nn][k]*w1[k*32 + ln];
  zs[nn][ln] = elu_f(acc);
  __syncthreads();
  int node = node0 + nn;
  if(ln < 2 && node < N){
    float o = b2[ln];
#pragma unroll
    for(int k = 0; k < 32; k++) o += zs[nn][k]*w2[k*2 + ln];
    out[(size_t)node*2 + ln] = o;
  }
}

// ---------------- launch ----------------

extern "C" void kernel_launch(void* const* d_in, const int* in_sizes, int n_in,
                              void* d_out, int out_size, void* d_ws, size_t ws_size,
                              hipStream_t stream)
{
  (void)n_in; (void)out_size; (void)ws_size;
  const float* x      = (const float*)d_in[0];
  const int*   ei     = (const int*)  d_in[1];
  const float* w_in   = (const float*)d_in[2];
  const float* b_in   = (const float*)d_in[3];
  const float* w_gcn  = (const float*)d_in[4];
  const float* b_gcn  = (const float*)d_in[5];
  const float* bn1_g  = (const float*)d_in[6];
  const float* bn1_b  = (const float*)d_in[7];
  const float* bn1_m  = (const float*)d_in[8];
  const float* bn1_v  = (const float*)d_in[9];
  const float* w_gat  = (const float*)d_in[10];
  const float* att_s  = (const float*)d_in[11];
  const float* att_d  = (const float*)d_in[12];
  const float* b_gat  = (const float*)d_in[13];
  const float* bn2_g  = (const float*)d_in[14];
  const float* bn2_b  = (const float*)d_in[15];
  const float* bn2_m  = (const float*)d_in[16];
  const float* bn2_v  = (const float*)d_in[17];
  const float* w_sl   = (const float*)d_in[18];
  const float* b_sage = (const float*)d_in[19];
  const float* w_sr   = (const float*)d_in[20];
  const float* bn3_g  = (const float*)d_in[21];
  const float* bn3_b  = (const float*)d_in[22];
  const float* bn3_m  = (const float*)d_in[23];
  const float* bn3_v  = (const float*)d_in[24];
  const float* w_res  = (const float*)d_in[25];
  const float* b_res  = (const float*)d_in[26];
  const float* w_c1   = (const float*)d_in[27];
  const float* b_c1   = (const float*)d_in[28];
  const float* w_c2   = (const float*)d_in[29];
  const float* b_c2   = (const float*)d_in[30];

  const int F_IN = 165;
  int N = in_sizes[0]/F_IN;
  int E = in_sizes[1]/2;
  const int* srcp = ei;
  const int* dstp = ei + E;
  int nb = (N + 1023) >> 10;

  char* p = (char*)d_ws;
  auto alloc = [&](size_t bytes) -> char* {
    char* q = p; p += (bytes + 255) & ~(size_t)255; return q;
  };
  ushort16* Acat  = (ushort16*)alloc((size_t)N*384*2);   // [mean_nb | h2 | h]
  ushort16* xb    = (ushort16*)alloc((size_t)N*192*2);   // later reused for h1
  ushort16* bufG  = (ushort16*)alloc((size_t)N*128*2);   // hw -> g -> (fp32 h3 overlays)
  float* a_src    = (float*)alloc((size_t)N*2*4);
  float* a_dst    = (float*)alloc((size_t)N*2*4);
  float* dinv     = (float*)alloc((size_t)N*4);
  int* cnt        = (int*)alloc((size_t)N*4);
  int* fill       = (int*)alloc((size_t)N*4);
  int* rowptr     = (int*)alloc((size_t)(N+1)*4);
  int* part       = (int*)alloc((size_t)N*4);
  int* bsum       = (int*)alloc(1024*4);
  int* boff       = (int*)alloc(1024*4);
  int* col        = (int*)alloc((size_t)E*4);
  float* s3       = (float*)alloc(64*4);
  float* bias3    = (float*)alloc(64*4);
  ushort16* pw_in  = (ushort16*)alloc(6*4*128*16);   // 48 KB
  ushort16* pw_gcn = (ushort16*)alloc(4*4*128*16);   // 32 KB
  ushort16* pw_gat = (ushort16*)alloc(4*4*128*16);
  ushort16* pw_cat = (ushort16*)alloc(12*4*64*16);   // 48 KB

  ushort16* h1 = xb;                 // xb dead after L0
  float*    h3 = (float*)bufG;       // g dead after gat_agg

  // cnt and fill are adjacent allocations: one memset covers both (incl. pad)
  hipMemsetAsync(cnt, 0, (size_t)((char*)(fill + N) - (char*)cnt), stream);

  count_deg_kernel<<<(E+255)/256, 256, 0, stream>>>(dstp, E, cnt);
  scan_blocks<<<nb, 1024, 0, stream>>>(cnt, N, part, bsum);
  scan_bsum<<<1, 1024, 0, stream>>>(bsum, nb, boff, rowptr, N);
  scan_add_dinv<<<(N+255)/256, 256, 0, stream>>>(part, boff, cnt, N, rowptr, dinv);
  scatter_kernel<<<(E+255)/256, 256, 0, stream>>>(srcp, dstp, E, rowptr, fill, col);

  cvt_x<<<(N*96 + 255)/256, 256, 0, stream>>>(x, (uint32*)xb, N*96);
  prep3<<<1, 64, 0, stream>>>(bn3_g, bn3_b, bn3_m, bn3_v, b_sage, b_res, s3, bias3);
  pack_all<<<320, 256, 0, stream>>>(w_in, w_gcn, w_gat, w_sl, w_sr, w_res, s3,
                                    pw_in, pw_gcn, pw_gat, pw_cat);

  int g128 = (N + 127)/128;
  int g256 = (N + 255)/256;

  // h = elu(x@w_in + b_in)  -> Acat[:,256:384]
  mfma_gemm<6,128,1><<<g128, 256, 0, stream>>>(xb, 192, (const uint4v*)pw_in, b_in,
                                               (void*)(Acat + 256), 384, N);
  // hw = h@w_gcn -> bufG
  mfma_gemm<4,128,0><<<g128, 256, 0, stream>>>(Acat + 256, 384, (const uint4v*)pw_gcn, nullptr,
                                               (void*)bufG, 128, N);
  // h1 = elu(bn1(agg(hw) + b_gcn))
  gcn_agg<<<N, 64, 0, stream>>>((const uint32*)bufG, rowptr, col, dinv, b_gcn,
                                bn1_g, bn1_b, bn1_m, bn1_v, (uint32*)h1, N);
  // g = h1@w_gat -> bufG
  mfma_gemm<4,128,0><<<g128, 256, 0, stream>>>(h1, 128, (const uint4v*)pw_gat, nullptr,
                                               (void*)bufG, 128, N);
  att_kernel<<<(N+3)/4, 64, 0, stream>>>((const uint32*)bufG, att_s, att_d, a_src, a_dst, N);
  // h2 -> Acat[:,128:256]
  gat_agg<<<N, 64, 0, stream>>>((const uint32*)bufG, a_src, a_dst, rowptr, col, b_gat,
                                bn2_g, bn2_b, bn2_m, bn2_v, (uint32*)Acat + 64, N);
  // mean_nb -> Acat[:,0:128]
  sage_mean<<<N, 64, 0, stream>>>((const uint32*)Acat + 64, rowptr, col, (uint32*)Acat, N);
  // h3 = elu((Acat @ [w_sl*s; w_sr*s; w_res]) + bias3)   (bn3 folded)
  mfma_gemm<12,64,2><<<g256, 256, 0, stream>>>(Acat, 384, (const uint4v*)pw_cat, bias3,
                                               (void*)h3, 64, N);
  classifier_kernel<<<(N+7)/8, 256, 0, stream>>>(h3, w_c1, b_c1, w_c2, b_c2, (float*)d_out, N);
}

// Round 5
// 419.618 us; speedup vs baseline: 1.2363x; 1.2363x over previous
//
#include <hip/hip_runtime.h>
#include <cstdint>
#include <cstddef>

#define BN_EPS 1e-5f

typedef __attribute__((ext_vector_type(8))) short short8v;
typedef __attribute__((ext_vector_type(4))) float float4v;
typedef __attribute__((ext_vector_type(4))) unsigned int uint4v;
typedef unsigned int uint32;
typedef unsigned short ushort16;

__device__ __forceinline__ float elu_f(float v){ return v > 0.f ? v : expm1f(v); }
__device__ __forceinline__ float leaky_f(float v){ return v > 0.f ? v : 0.2f*v; }
__device__ __forceinline__ uint32 f2bf(float f){
  uint32 b = __float_as_uint(f);
  return (b + 0x7fffu + ((b >> 16) & 1u)) >> 16;        // RNE
}
__device__ __forceinline__ float bflo(uint32 u){ return __uint_as_float(u << 16); }
__device__ __forceinline__ float bfhi(uint32 u){ return __uint_as_float(u & 0xffff0000u); }
__device__ __forceinline__ float readlane_f(float v, int l){
  return __int_as_float(__builtin_amdgcn_readlane(__float_as_int(v), l));
}
// monotonic float<->uint encode for atomicMax on floats (deterministic)
__device__ __forceinline__ uint32 fenc(float f){
  uint32 u = __float_as_uint(f);
  return (u >> 31) ? ~u : (u | 0x80000000u);
}
__device__ __forceinline__ float fdec(uint32 e){
  return (e & 0x80000000u) ? __uint_as_float(e & 0x7fffffffu) : __uint_as_float(~e);
}

// ---------------- graph preprocessing: CSR by dst ----------------

__global__ void count_deg_kernel(const int* __restrict__ dst, int E, int* __restrict__ cnt){
  int i = blockIdx.x*blockDim.x + threadIdx.x;
  if(i < E) atomicAdd(&cnt[dst[i]], 1);
}

__global__ __launch_bounds__(1024) void scan_blocks(const int* __restrict__ cnt, int n,
                                                    int* __restrict__ part, int* __restrict__ bsum){
  __shared__ int wsum[16];
  int tid = threadIdx.x, lane = tid & 63, w = tid >> 6;
  int i = blockIdx.x*1024 + tid;
  int v = (i < n) ? cnt[i] : 0;
  int sv = v;
#pragma unroll
  for(int o = 1; o < 64; o <<= 1){
    int u = __shfl_up(sv, o);
    if(lane >= o) sv += u;
  }
  if(lane == 63) wsum[w] = sv;
  __syncthreads();
  int woff = 0;
#pragma unroll
  for(int q = 0; q < 16; q++) woff += (q < w) ? wsum[q] : 0;
  if(i < n) part[i] = woff + sv - v;
  if(tid == 1023) bsum[blockIdx.x] = woff + sv;
}

__global__ __launch_bounds__(1024) void scan_bsum(const int* __restrict__ bsum, int nb,
                                                  int* __restrict__ boff, int* __restrict__ rowptr, int n){
  __shared__ int wsum[16];
  int tid = threadIdx.x, lane = tid & 63, w = tid >> 6;
  int v = (tid < nb) ? bsum[tid] : 0;
  int sv = v;
#pragma unroll
  for(int o = 1; o < 64; o <<= 1){
    int u = __shfl_up(sv, o);
    if(lane >= o) sv += u;
  }
  if(lane == 63) wsum[w] = sv;
  __syncthreads();
  int woff = 0;
#pragma unroll
  for(int q = 0; q < 16; q++) woff += (q < w) ? wsum[q] : 0;
  if(tid < nb) boff[tid] = woff + sv - v;
  if(tid == 1023) rowptr[n] = woff + sv;
}

__global__ void scan_add_dinv(const int* __restrict__ part, const int* __restrict__ boff,
                              const int* __restrict__ cnt, int n,
                              int* __restrict__ rowptr, float* __restrict__ dinv){
  int i = blockIdx.x*blockDim.x + threadIdx.x;
  if(i < n){
    rowptr[i] = part[i] + boff[i >> 10];
    dinv[i] = rsqrtf((float)cnt[i] + 1.0f);   // deg includes self loop
  }
}

// scatter also records CSR position per edge and the GCN edge weight dinv[src]
__global__ void scatter_kernel(const int* __restrict__ src, const int* __restrict__ dst, int E,
                               const int* __restrict__ rowptr, const float* __restrict__ dinv,
                               int* __restrict__ fill, int* __restrict__ col,
                               int* __restrict__ pos, float* __restrict__ gw){
  int i = blockIdx.x*blockDim.x + threadIdx.x;
  if(i < E){
    int s = src[i], d = dst[i];
    int p = rowptr[d] + atomicAdd(&fill[d], 1);
    col[p] = s;
    pos[i] = p;
    gw[p] = dinv[s];
  }
}

// ---------------- x -> bf16, K padded 165 -> 192, packed uint writes ----------------

__global__ __launch_bounds__(256) void cvt_x(const float* __restrict__ x, uint32* __restrict__ xb, int total){
  int idx = blockIdx.x*256 + threadIdx.x;     // over N*96 packed uints
  if(idx >= total) return;
  int row = idx/96;
  int cp = idx - row*96;
  int c = cp*2;
  const float* xr = x + (size_t)row*165;
  float v0 = (c < 165) ? xr[c] : 0.f;
  float v1 = (c < 164) ? xr[c+1] : 0.f;
  xb[idx] = f2bf(v0) | (f2bf(v1) << 16);
}

// ---------------- BN folding: per-channel scales + combined biases ----------------

__global__ void prep_scales(const float* __restrict__ bn1_g, const float* __restrict__ bn1_b,
    const float* __restrict__ bn1_m, const float* __restrict__ bn1_v, const float* __restrict__ b_gcn,
    const float* __restrict__ bn2_g, const float* __restrict__ bn2_b,
    const float* __restrict__ bn2_m, const float* __restrict__ bn2_v, const float* __restrict__ b_gat,
    const float* __restrict__ att_s, const float* __restrict__ att_d,
    const float* __restrict__ bn3_g, const float* __restrict__ bn3_b,
    const float* __restrict__ bn3_m, const float* __restrict__ bn3_v,
    const float* __restrict__ b_sage, const float* __restrict__ b_res,
    float* __restrict__ s1, float* __restrict__ b1c,
    float* __restrict__ s2, float* __restrict__ b2c,
    float* __restrict__ atts2, float* __restrict__ attd2,
    float* __restrict__ s3, float* __restrict__ bias3){
  int c = threadIdx.x;   // 128
  float v1 = bn1_g[c]*rsqrtf(bn1_v[c] + BN_EPS);
  s1[c] = v1;
  b1c[c] = (b_gcn[c] - bn1_m[c])*v1 + bn1_b[c];
  float v2 = bn2_g[c]*rsqrtf(bn2_v[c] + BN_EPS);
  s2[c] = v2;
  b2c[c] = (b_gat[c] - bn2_m[c])*v2 + bn2_b[c];
  atts2[c] = att_s[c]/v2;
  attd2[c] = att_d[c]/v2;
  if(c < 64){
    float v3 = bn3_g[c]*rsqrtf(bn3_v[c] + BN_EPS);
    s3[c] = v3;
    bias3[c] = (b_sage[c] - bn3_m[c])*v3 + bn3_b[c] + b_res[c];
  }
}

// ---------------- weight packing (one launch): packed[kgrp][col][8] bf16 ----------------

__device__ __forceinline__ void pack_region(const float* __restrict__ W, int K, int NOUT, int kbase, int idx,
                                            const float* __restrict__ scale, ushort16* __restrict__ out){
  int k = idx / NOUT, c = idx - k*NOUT;
  float v = (k < K) ? W[(size_t)k*NOUT + c] : 0.f;
  if(scale) v *= scale[c];
  int pk = kbase + k;
  out[(size_t)(pk >> 3)*NOUT*8 + (size_t)c*8 + (pk & 7)] = (ushort16)f2bf(v);
}

__global__ __launch_bounds__(256) void pack_all(const float* __restrict__ w_in, const float* __restrict__ w_gcn,
    const float* __restrict__ w_gat, const float* __restrict__ w_sl, const float* __restrict__ w_sr,
    const float* __restrict__ w_res,
    const float* __restrict__ s1, const float* __restrict__ s2, const float* __restrict__ s3,
    ushort16* __restrict__ pw_in, ushort16* __restrict__ pw_gcn,
    ushort16* __restrict__ pw_gat, ushort16* __restrict__ pw_cat){
  int b = blockIdx.x, t = threadIdx.x;
  if(b < 96)       pack_region(w_in,  165, 128, 0,   b*256 + t,        nullptr, pw_in);
  else if(b < 160) pack_region(w_gcn, 128, 128, 0,   (b-96)*256 + t,   s1,      pw_gcn);
  else if(b < 224) pack_region(w_gat, 128, 128, 0,   (b-160)*256 + t,  s2,      pw_gat);
  else if(b < 256) pack_region(w_sl,  128, 64,  0,   (b-224)*256 + t,  s3,      pw_cat);
  else if(b < 288) pack_region(w_sr,  128, 64,  128, (b-256)*256 + t,  s3,      pw_cat);
  else             pack_region(w_res, 128, 64,  256, (b-288)*256 + t,  nullptr, pw_cat);
}

// ---------------- MFMA bf16 GEMM (unchanged from round 3) ----------------

template<int KSTEPS, int NOUT, int EPI>
__global__ __launch_bounds__(256) void mfma_gemm(
    const ushort16* __restrict__ A, int lda,
    const uint4v* __restrict__ pw,
    const float* __restrict__ bias,
    void* __restrict__ out, int ldo, int N)
{
  constexpr int LDSV = KSTEPS*4*NOUT;
  __shared__ uint4v wlds[LDSV];
  int t = threadIdx.x;
#pragma unroll
  for(int q = 0; q < LDSV/256; q++)
    wlds[q*256 + t] = pw[q*256 + t];
  __syncthreads();

  int wid = t >> 6, lane = t & 63;
  int wm, wn;
  if(NOUT == 128){ wm = wid >> 1; wn = wid & 1; } else { wm = wid; wn = 0; }
  constexpr int MTILE = (NOUT == 128) ? 128 : 256;
  long row0 = (long)blockIdx.x*MTILE + wm*64;
  int l15 = lane & 15, lk = lane >> 4;
  int wn64 = wn*64;
  const ushort16* wl = (const ushort16*)wlds;

  float4v acc[4][4];
#pragma unroll
  for(int fm = 0; fm < 4; fm++)
#pragma unroll
    for(int fn = 0; fn < 4; fn++) acc[fm][fn] = (float4v){0.f,0.f,0.f,0.f};

  const ushort16* abase[4];
#pragma unroll
  for(int fm = 0; fm < 4; fm++){
    long r = row0 + fm*16 + l15;
    if(r > (long)N - 1) r = (long)N - 1;
    abase[fm] = A + r*(size_t)lda + lk*8;
  }

  short8v a[4];
#pragma unroll
  for(int fm = 0; fm < 4; fm++) a[fm] = *(const short8v*)(abase[fm]);

#pragma unroll
  for(int ks = 0; ks < KSTEPS; ks++){
    short8v b[4];
#pragma unroll
    for(int fn = 0; fn < 4; fn++){
      int c = wn64 + fn*16 + l15;
      b[fn] = *(const short8v*)(wl + ((size_t)((ks*4 + lk)*NOUT + c))*8);
    }
    short8v an[4];
    if(ks + 1 < KSTEPS){
#pragma unroll
      for(int fm = 0; fm < 4; fm++) an[fm] = *(const short8v*)(abase[fm] + (ks + 1)*32);
    }
#pragma unroll
    for(int fm = 0; fm < 4; fm++)
#pragma unroll
      for(int fn = 0; fn < 4; fn++)
        acc[fm][fn] = __builtin_amdgcn_mfma_f32_16x16x32_bf16(a[fm], b[fn], acc[fm][fn], 0, 0, 0);
    if(ks + 1 < KSTEPS){
#pragma unroll
      for(int fm = 0; fm < 4; fm++) a[fm] = an[fm];
    }
  }

#pragma unroll
  for(int fm = 0; fm < 4; fm++){
#pragma unroll
    for(int rr = 0; rr < 4; rr++){
      long r = row0 + fm*16 + lk*4 + rr;
      if(r < N){
#pragma unroll
        for(int fn = 0; fn < 4; fn++){
          int c = wn64 + fn*16 + l15;
          float v = acc[fm][fn][rr];
          if constexpr(EPI >= 1){ v += bias[c]; v = elu_f(v); }
          if constexpr(EPI == 2) ((float*)out)[r*(size_t)ldo + c] = v;
          else ((ushort16*)out)[r*(size_t)ldo + c] = (ushort16)f2bf(v);
        }
      }
    }
  }
}

// ---------------- GCN aggregation + folded BN1 + ELU ----------------
// grid-stride, 4 waves/block, 1 node per wave, scalar (readlane) row gathers, no LDS/barriers

__global__ __launch_bounds__(256) void gcn_agg(const uint32* __restrict__ hw,   // stride 64 uints
    const int* __restrict__ rowptr, const int* __restrict__ col, const float* __restrict__ gw,
    const float* __restrict__ dinv, const float* __restrict__ b1c,
    uint32* __restrict__ h1, int N)
{
  int t = threadIdx.x & 63;
  int w = __builtin_amdgcn_readfirstlane(threadIdx.x >> 6);
  float2 bc = ((const float2*)b1c)[t];
  int stride = gridDim.x*4;
  for(int i = blockIdx.x*4 + w; i < N; i += stride){
    int beg = rowptr[i], end = rowptr[i+1];
    float di = dinv[i];
    float a0 = 0.f, a1 = 0.f;
    for(int c0 = beg; c0 < end; c0 += 64){
      int p = c0 + t;
      int cl = end - c0; if(cl > 64) cl = 64;
      int s = 0; float wv = 0.f;
      if(p < end){ s = col[p]; wv = gw[p]; }
      for(int q = 0; q < cl; q++){
        int row = __builtin_amdgcn_readlane(s, q);
        float wq = readlane_f(wv, q);
        uint32 u = hw[(size_t)row*64 + t];
        a0 += wq*bflo(u); a1 += wq*bfhi(u);
      }
    }
    uint32 su = hw[(size_t)i*64 + t];
    float v0 = (a0 + bflo(su)*di)*di + bc.x;
    float v1 = (a1 + bfhi(su)*di)*di + bc.y;
    h1[(size_t)i*64 + t] = f2bf(elu_f(v0)) | (f2bf(elu_f(v1)) << 16);
  }
}

// ---------------- GAT attention scalars + self logits + segment-max init ----------------

__global__ __launch_bounds__(256) void att_kernel(const uint32* __restrict__ g,
    const float* __restrict__ atts2, const float* __restrict__ attd2,
    float* __restrict__ a_src, float* __restrict__ a_dst,
    float* __restrict__ ess, uint32* __restrict__ Mint, int N)
{
  int t = threadIdx.x & 63;
  int w = __builtin_amdgcn_readfirstlane(threadIdx.x >> 6);
  float2 as2 = ((const float2*)atts2)[t];
  float2 ad2 = ((const float2*)attd2)[t];
  int stride = gridDim.x*4;
  for(int i = blockIdx.x*4 + w; i < N; i += stride){
    uint32 u = g[(size_t)i*64 + t];
    float g0 = bflo(u), g1 = bfhi(u);
    float s1 = g0*as2.x + g1*as2.y;
    float s2 = g0*ad2.x + g1*ad2.y;
#pragma unroll
    for(int o = 16; o > 0; o >>= 1){ s1 += __shfl_xor(s1, o); s2 += __shfl_xor(s2, o); }
    if((t & 31) == 0){
      int h = t >> 5;
      a_src[2*i + h] = s1;
      a_dst[2*i + h] = s2;
      float es = leaky_f(s1 + s2);
      ess[2*i + h] = es;
      Mint[2*i + h] = fenc(es);
    }
  }
}

// ---------------- per-edge logits + segment max (deterministic atomicMax) ----------------

__global__ void edge_logit(const int* __restrict__ src, const int* __restrict__ dst,
                           const int* __restrict__ pos, int E,
                           const float* __restrict__ a_src, const float* __restrict__ a_dst,
                           float2* __restrict__ lcsr, uint32* __restrict__ Mint){
  int i = blockIdx.x*blockDim.x + threadIdx.x;
  if(i >= E) return;
  int s = src[i], d = dst[i], p = pos[i];
  float2 as = ((const float2*)a_src)[s];
  float2 ad = ((const float2*)a_dst)[d];
  float l0 = leaky_f(as.x + ad.x);
  float l1 = leaky_f(as.y + ad.y);
  lcsr[p] = make_float2(l0, l1);
  atomicMax(&Mint[2*d],   fenc(l0));
  atomicMax(&Mint[2*d+1], fenc(l1));
}

// ---------------- GAT gather: exp + denom + weighted sum + folded BN2 + ELU ----------------
// writes h2 (bf16) into Acat[:,128:256]  (out pre-offset, stride 192 uints)

__global__ __launch_bounds__(256) void gat_gather(const uint32* __restrict__ g,   // stride 64
    const int* __restrict__ rowptr, const int* __restrict__ col,
    const float2* __restrict__ lcsr, const uint32* __restrict__ Mint, const float* __restrict__ ess,
    const float* __restrict__ b2c, uint32* __restrict__ h2out, int N)
{
  int t = threadIdx.x & 63;
  int w = __builtin_amdgcn_readfirstlane(threadIdx.x >> 6);
  float2 bc = ((const float2*)b2c)[t];
  int hl = t >> 5;
  int stride = gridDim.x*4;
  for(int i = blockIdx.x*4 + w; i < N; i += stride){
    int beg = rowptr[i], end = rowptr[i+1];
    float M0 = fdec(Mint[2*i]), M1 = fdec(Mint[2*i+1]);
    float es0 = ess[2*i], es1 = ess[2*i+1];
    float d0 = 0.f, d1 = 0.f, a0 = 0.f, a1 = 0.f;
    for(int c0 = beg; c0 < end; c0 += 64){
      int p = c0 + t;
      int cl = end - c0; if(cl > 64) cl = 64;
      float e0 = 0.f, e1 = 0.f; int s = 0;
      if(p < end){
        float2 l = lcsr[p];
        e0 = __expf(l.x - M0); e1 = __expf(l.y - M1);
        s = col[p];
      }
      d0 += e0; d1 += e1;
      for(int q = 0; q < cl; q++){
        int row = __builtin_amdgcn_readlane(s, q);
        float w0q = readlane_f(e0, q);
        float w1q = readlane_f(e1, q);
        float wq = hl ? w1q : w0q;
        uint32 u = g[(size_t)row*64 + t];
        a0 += wq*bflo(u); a1 += wq*bfhi(u);
      }
    }
#pragma unroll
    for(int o = 32; o > 0; o >>= 1){ d0 += __shfl_xor(d0, o); d1 += __shfl_xor(d1, o); }
    float sw0 = __expf(es0 - M0), sw1 = __expf(es1 - M1);
    float rD = 1.f/(((hl ? d1 : d0) + (hl ? sw1 : sw0)) + 1e-16f);
    float sw = hl ? sw1 : sw0;
    uint32 su = g[(size_t)i*64 + t];
    float v0 = (a0 + sw*bflo(su))*rD + bc.x;
    float v1 = (a1 + sw*bfhi(su))*rD + bc.y;
    h2out[(size_t)i*192 + t] = f2bf(elu_f(v0)) | (f2bf(elu_f(v1)) << 16);
  }
}

// ---------------- SAGE mean (no self loops), inside Acat ----------------

__global__ __launch_bounds__(256) void sage_mean(const uint32* __restrict__ h2,  // pre-offset +64, stride 192
    const int* __restrict__ rowptr, const int* __restrict__ col,
    uint32* __restrict__ mout, int N)                                             // stride 192
{
  int t = threadIdx.x & 63;
  int w = __builtin_amdgcn_readfirstlane(threadIdx.x >> 6);
  int stride = gridDim.x*4;
  for(int i = blockIdx.x*4 + w; i < N; i += stride){
    int beg = rowptr[i], end = rowptr[i+1];
    float a0 = 0.f, a1 = 0.f;
    for(int c0 = beg; c0 < end; c0 += 64){
      int p = c0 + t;
      int cl = end - c0; if(cl > 64) cl = 64;
      int s = (p < end) ? col[p] : 0;
      for(int q = 0; q < cl; q++){
        int row = __builtin_amdgcn_readlane(s, q);
        uint32 u = h2[(size_t)row*192 + t];
        a0 += bflo(u); a1 += bfhi(u);
      }
    }
    float inv = 1.f/fmaxf((float)(end - beg), 1.f);
    mout[(size_t)i*192 + t] = f2bf(a0*inv) | (f2bf(a1*inv) << 16);
  }
}

// ---------------- classifier: out = elu(h3@w1+b1)@w2 + b2 ----------------

__global__ __launch_bounds__(256) void classifier_kernel(const float* __restrict__ h3,
    const float* __restrict__ w1, const float* __restrict__ b1,
    const float* __restrict__ w2, const float* __restrict__ b2,
    float* __restrict__ out, int N)
{
  __shared__ float hs[8][64];
  __shared__ float zs[8][32];
  int node0 = blockIdx.x*8;
  int t = threadIdx.x;
#pragma unroll
  for(int q = 0; q < 2; q++){
    int e = t + q*256;
    int r = e >> 6, c = e & 63;
    int nd = node0 + r;
    hs[r][c] = (nd < N) ? h3[(size_t)nd*64 + c] : 0.f;
  }
  __syncthreads();
  int nn = t >> 5, ln = t & 31;
  float acc = b1[ln];
#pragma unroll
  for(int k = 0; k < 64; k++) acc += hs[nn][k]*w1[k*32 + ln];
  zs[nn][ln] = elu_f(acc);
  __syncthreads();
  int node = node0 + nn;
  if(ln < 2 && node < N){
    float o = b2[ln];
#pragma unroll
    for(int k = 0; k < 32; k++) o += zs[nn][k]*w2[k*2 + ln];
    out[(size_t)node*2 + ln] = o;
  }
}

// ---------------- launch ----------------

extern "C" void kernel_launch(void* const* d_in, const int* in_sizes, int n_in,
                              void* d_out, int out_size, void* d_ws, size_t ws_size,
                              hipStream_t stream)
{
  (void)n_in; (void)out_size; (void)ws_size;
  const float* x      = (const float*)d_in[0];
  const int*   ei     = (const int*)  d_in[1];
  const float* w_in   = (const float*)d_in[2];
  const float* b_in   = (const float*)d_in[3];
  const float* w_gcn  = (const float*)d_in[4];
  const float* b_gcn  = (const float*)d_in[5];
  const float* bn1_g  = (const float*)d_in[6];
  const float* bn1_b  = (const float*)d_in[7];
  const float* bn1_m  = (const float*)d_in[8];
  const float* bn1_v  = (const float*)d_in[9];
  const float* w_gat  = (const float*)d_in[10];
  const float* att_s  = (const float*)d_in[11];
  const float* att_d  = (const float*)d_in[12];
  const float* b_gat  = (const float*)d_in[13];
  const float* bn2_g  = (const float*)d_in[14];
  const float* bn2_b  = (const float*)d_in[15];
  const float* bn2_m  = (const float*)d_in[16];
  const float* bn2_v  = (const float*)d_in[17];
  const float* w_sl   = (const float*)d_in[18];
  const float* b_sage = (const float*)d_in[19];
  const float* w_sr   = (const float*)d_in[20];
  const float* bn3_g  = (const float*)d_in[21];
  const float* bn3_b  = (const float*)d_in[22];
  const float* bn3_m  = (const float*)d_in[23];
  const float* bn3_v  = (const float*)d_in[24];
  const float* w_res  = (const float*)d_in[25];
  const float* b_res  = (const float*)d_in[26];
  const float* w_c1   = (const float*)d_in[27];
  const float* b_c1   = (const float*)d_in[28];
  const float* w_c2   = (const float*)d_in[29];
  const float* b_c2   = (const float*)d_in[30];

  const int F_IN = 165;
  int N = in_sizes[0]/F_IN;
  int E = in_sizes[1]/2;
  const int* srcp = ei;
  const int* dstp = ei + E;
  int nb = (N + 1023) >> 10;

  char* p = (char*)d_ws;
  auto alloc = [&](size_t bytes) -> char* {
    char* q = p; p += (bytes + 255) & ~(size_t)255; return q;
  };
  ushort16* Acat  = (ushort16*)alloc((size_t)N*384*2);   // [mean_nb | h2 | h]
  ushort16* xb    = (ushort16*)alloc((size_t)N*192*2);   // later reused for h1
  ushort16* bufG  = (ushort16*)alloc((size_t)N*128*2);   // hw -> g -> (fp32 h3 overlays)
  float* a_src    = (float*)alloc((size_t)N*2*4);
  float* a_dst    = (float*)alloc((size_t)N*2*4);
  float* ess      = (float*)alloc((size_t)N*2*4);
  uint32* Mint    = (uint32*)alloc((size_t)N*2*4);
  float* dinv     = (float*)alloc((size_t)N*4);
  int* cnt        = (int*)alloc((size_t)N*4);
  int* fill       = (int*)alloc((size_t)N*4);
  int* rowptr     = (int*)alloc((size_t)(N+1)*4);
  int* part       = (int*)alloc((size_t)N*4);
  int* bsum       = (int*)alloc(1024*4);
  int* boff       = (int*)alloc(1024*4);
  int* col        = (int*)alloc((size_t)E*4);
  int* pos        = (int*)alloc((size_t)E*4);
  float* gw       = (float*)alloc((size_t)E*4);
  float2* lcsr    = (float2*)alloc((size_t)E*8);
  float* s1       = (float*)alloc(128*4);
  float* b1c      = (float*)alloc(128*4);
  float* s2       = (float*)alloc(128*4);
  float* b2c      = (float*)alloc(128*4);
  float* atts2    = (float*)alloc(128*4);
  float* attd2    = (float*)alloc(128*4);
  float* s3       = (float*)alloc(64*4);
  float* bias3    = (float*)alloc(64*4);
  ushort16* pw_in  = (ushort16*)alloc(6*4*128*16);   // 48 KB
  ushort16* pw_gcn = (ushort16*)alloc(4*4*128*16);   // 32 KB
  ushort16* pw_gat = (ushort16*)alloc(4*4*128*16);
  ushort16* pw_cat = (ushort16*)alloc(12*4*64*16);   // 48 KB

  ushort16* h1 = xb;                 // xb dead after L0
  float*    h3 = (float*)bufG;       // g dead after gat_gather

  // cnt and fill are adjacent allocations: one memset covers both (incl. pad)
  hipMemsetAsync(cnt, 0, (size_t)((char*)(fill + N) - (char*)cnt), stream);

  count_deg_kernel<<<(E+255)/256, 256, 0, stream>>>(dstp, E, cnt);
  scan_blocks<<<nb, 1024, 0, stream>>>(cnt, N, part, bsum);
  scan_bsum<<<1, 1024, 0, stream>>>(bsum, nb, boff, rowptr, N);
  scan_add_dinv<<<(N+255)/256, 256, 0, stream>>>(part, boff, cnt, N, rowptr, dinv);
  scatter_kernel<<<(E+255)/256, 256, 0, stream>>>(srcp, dstp, E, rowptr, dinv, fill, col, pos, gw);

  cvt_x<<<(N*96 + 255)/256, 256, 0, stream>>>(x, (uint32*)xb, N*96);
  prep_scales<<<1, 128, 0, stream>>>(bn1_g, bn1_b, bn1_m, bn1_v, b_gcn,
                                     bn2_g, bn2_b, bn2_m, bn2_v, b_gat,
                                     att_s, att_d,
                                     bn3_g, bn3_b, bn3_m, bn3_v, b_sage, b_res,
                                     s1, b1c, s2, b2c, atts2, attd2, s3, bias3);
  pack_all<<<320, 256, 0, stream>>>(w_in, w_gcn, w_gat, w_sl, w_sr, w_res,
                                    s1, s2, s3, pw_in, pw_gcn, pw_gat, pw_cat);

  int g128 = (N + 127)/128;
  int g256 = (N + 255)/256;
  int gagg = (N + 3)/4; if(gagg > 2048) gagg = 2048;

  // h = elu(x@w_in + b_in)  -> Acat[:,256:384]
  mfma_gemm<6,128,1><<<g128, 256, 0, stream>>>(xb, 192, (const uint4v*)pw_in, b_in,
                                               (void*)(Acat + 256), 384, N);
  // hw' = h@(w_gcn*s1) -> bufG
  mfma_gemm<4,128,0><<<g128, 256, 0, stream>>>(Acat + 256, 384, (const uint4v*)pw_gcn, nullptr,
                                               (void*)bufG, 128, N);
  // h1 = elu(agg(hw')*di + b1c)
  gcn_agg<<<gagg, 256, 0, stream>>>((const uint32*)bufG, rowptr, col, gw, dinv, b1c,
                                    (uint32*)h1, N);
  // g' = h1@(w_gat*s2) -> bufG
  mfma_gemm<4,128,0><<<g128, 256, 0, stream>>>(h1, 128, (const uint4v*)pw_gat, nullptr,
                                               (void*)bufG, 128, N);
  // attention scalars + self logits + M init
  att_kernel<<<gagg, 256, 0, stream>>>((const uint32*)bufG, atts2, attd2,
                                       a_src, a_dst, ess, Mint, N);
  // per-edge logits + segment max
  edge_logit<<<(E+255)/256, 256, 0, stream>>>(srcp, dstp, pos, E, a_src, a_dst, lcsr, Mint);
  // h2 -> Acat[:,128:256]
  gat_gather<<<gagg, 256, 0, stream>>>((const uint32*)bufG, rowptr, col, lcsr, Mint, ess,
                                       b2c, (uint32*)Acat + 64, N);
  // mean_nb -> Acat[:,0:128]
  sage_mean<<<gagg, 256, 0, stream>>>((const uint32*)Acat + 64, rowptr, col, (uint32*)Acat, N);
  // h3 = elu((Acat @ [w_sl*s3; w_sr*s3; w_res]) + bias3)   (bn3 folded)
  mfma_gemm<12,64,2><<<g256, 256, 0, stream>>>(Acat, 384, (const uint4v*)pw_cat, bias3,
                                               (void*)h3, 64, N);
  classifier_kernel<<<(N+7)/8, 256, 0, stream>>>(h3, w_c1, b_c1, w_c2, b_c2, (float*)d_out, N);
}

// Round 7
// 378.331 us; speedup vs baseline: 1.3712x; 1.1091x over previous
//
#include <hip/hip_runtime.h>
#include <cstdint>
#include <cstddef>

#define BN_EPS 1e-5f

typedef __attribute__((ext_vector_type(8))) short short8v;
typedef __attribute__((ext_vector_type(4))) float float4v;
typedef __attribute__((ext_vector_type(4))) unsigned int uint4v;
typedef unsigned int uint32;
typedef unsigned short ushort16;

__device__ __forceinline__ float elu_f(float v){ return v > 0.f ? v : expm1f(v); }
__device__ __forceinline__ float leaky_f(float v){ return v > 0.f ? v : 0.2f*v; }
__device__ __forceinline__ uint32 f2bf(float f){
  uint32 b = __float_as_uint(f);
  return (b + 0x7fffu + ((b >> 16) & 1u)) >> 16;        // RNE
}
__device__ __forceinline__ float bflo(uint32 u){ return __uint_as_float(u << 16); }
__device__ __forceinline__ float bfhi(uint32 u){ return __uint_as_float(u & 0xffff0000u); }
__device__ __forceinline__ float readlane_f(float v, int l){
  return __int_as_float(__builtin_amdgcn_readlane(__float_as_int(v), l));
}
// monotonic float<->uint encode for atomicMax on floats (deterministic)
__device__ __forceinline__ uint32 fenc(float f){
  uint32 u = __float_as_uint(f);
  return (u >> 31) ? ~u : (u | 0x80000000u);
}
__device__ __forceinline__ float fdec(uint32 e){
  return (e & 0x80000000u) ? __uint_as_float(e & 0x7fffffffu) : __uint_as_float(~e);
}

// ---------------- graph preprocessing: CSR by dst ----------------

__global__ void count_deg_kernel(const int* __restrict__ dst, int E, int* __restrict__ cnt){
  int i = blockIdx.x*blockDim.x + threadIdx.x;
  if(i < E) atomicAdd(&cnt[dst[i]], 1);
}

__global__ __launch_bounds__(1024) void scan_blocks(const int* __restrict__ cnt, int n,
                                                    int* __restrict__ part, int* __restrict__ bsum){
  __shared__ int wsum[16];
  int tid = threadIdx.x, lane = tid & 63, w = tid >> 6;
  int i = blockIdx.x*1024 + tid;
  int v = (i < n) ? cnt[i] : 0;
  int sv = v;
#pragma unroll
  for(int o = 1; o < 64; o <<= 1){
    int u = __shfl_up(sv, o);
    if(lane >= o) sv += u;
  }
  if(lane == 63) wsum[w] = sv;
  __syncthreads();
  int woff = 0;
#pragma unroll
  for(int q = 0; q < 16; q++) woff += (q < w) ? wsum[q] : 0;
  if(i < n) part[i] = woff + sv - v;
  if(tid == 1023) bsum[blockIdx.x] = woff + sv;
}

__global__ __launch_bounds__(1024) void scan_bsum(const int* __restrict__ bsum, int nb,
                                                  int* __restrict__ boff, int* __restrict__ rowptr, int n){
  __shared__ int wsum[16];
  int tid = threadIdx.x, lane = tid & 63, w = tid >> 6;
  int v = (tid < nb) ? bsum[tid] : 0;
  int sv = v;
#pragma unroll
  for(int o = 1; o < 64; o <<= 1){
    int u = __shfl_up(sv, o);
    if(lane >= o) sv += u;
  }
  if(lane == 63) wsum[w] = sv;
  __syncthreads();
  int woff = 0;
#pragma unroll
  for(int q = 0; q < 16; q++) woff += (q < w) ? wsum[q] : 0;
  if(tid < nb) boff[tid] = woff + sv - v;
  if(tid == 1023) rowptr[n] = woff + sv;
}

__global__ void scan_add_dinv(const int* __restrict__ part, const int* __restrict__ boff,
                              const int* __restrict__ cnt, int n,
                              int* __restrict__ rowptr, float* __restrict__ dinv){
  int i = blockIdx.x*blockDim.x + threadIdx.x;
  if(i < n){
    rowptr[i] = part[i] + boff[i >> 10];
    dinv[i] = rsqrtf((float)cnt[i] + 1.0f);   // deg includes self loop
  }
}

__global__ void scatter_kernel(const int* __restrict__ src, const int* __restrict__ dst, int E,
                               const int* __restrict__ rowptr, int* __restrict__ fill,
                               int* __restrict__ col, int* __restrict__ pos){
  int i = blockIdx.x*blockDim.x + threadIdx.x;
  if(i < E){
    int s = src[i], d = dst[i];
    int p = rowptr[d] + atomicAdd(&fill[d], 1);
    col[p] = s;
    pos[i] = p;
  }
}

// ---------------- x -> bf16, K padded 165 -> 192, uint2 writes ----------------

__global__ __launch_bounds__(256) void cvt_x(const float* __restrict__ x, uint2* __restrict__ xb, int total){
  int idx = blockIdx.x*256 + threadIdx.x;     // over N*48 uint2
  if(idx >= total) return;
  int row = idx/48;
  int cp = idx - row*48;
  int c = cp*4;
  const float* xr = x + (size_t)row*165;
  float v0 = (c   < 165) ? xr[c]   : 0.f;
  float v1 = (c+1 < 165) ? xr[c+1] : 0.f;
  float v2 = (c+2 < 165) ? xr[c+2] : 0.f;
  float v3 = (c+3 < 165) ? xr[c+3] : 0.f;
  xb[idx] = make_uint2(f2bf(v0) | (f2bf(v1) << 16), f2bf(v2) | (f2bf(v3) << 16));
}

// ---------------- BN folding: per-channel scales + combined biases ----------------

__global__ void prep_scales(const float* __restrict__ bn1_g, const float* __restrict__ bn1_b,
    const float* __restrict__ bn1_m, const float* __restrict__ bn1_v, const float* __restrict__ b_gcn,
    const float* __restrict__ bn2_g, const float* __restrict__ bn2_b,
    const float* __restrict__ bn2_m, const float* __restrict__ bn2_v, const float* __restrict__ b_gat,
    const float* __restrict__ att_s, const float* __restrict__ att_d,
    const float* __restrict__ bn3_g, const float* __restrict__ bn3_b,
    const float* __restrict__ bn3_m, const float* __restrict__ bn3_v,
    const float* __restrict__ b_sage, const float* __restrict__ b_res,
    float* __restrict__ s1, float* __restrict__ b1c,
    float* __restrict__ s2, float* __restrict__ b2c,
    float* __restrict__ atts2, float* __restrict__ attd2,
    float* __restrict__ s3, float* __restrict__ bias3){
  int c = threadIdx.x;   // 128
  float v1 = bn1_g[c]*rsqrtf(bn1_v[c] + BN_EPS);
  s1[c] = v1;
  b1c[c] = (b_gcn[c] - bn1_m[c])*v1 + bn1_b[c];
  float v2 = bn2_g[c]*rsqrtf(bn2_v[c] + BN_EPS);
  s2[c] = v2;
  b2c[c] = (b_gat[c] - bn2_m[c])*v2 + bn2_b[c];
  atts2[c] = att_s[c]/v2;
  attd2[c] = att_d[c]/v2;
  if(c < 64){
    float v3 = bn3_g[c]*rsqrtf(bn3_v[c] + BN_EPS);
    s3[c] = v3;
    bias3[c] = (b_sage[c] - bn3_m[c])*v3 + bn3_b[c] + b_res[c];
  }
}

// ---------------- weight packing (one launch): packed[kgrp][col][8] bf16 ----------------

__device__ __forceinline__ void pack_region(const float* __restrict__ W, int K, int NOUT, int kbase, int idx,
                                            const float* __restrict__ scale, ushort16* __restrict__ out){
  int k = idx / NOUT, c = idx - k*NOUT;
  float v = (k < K) ? W[(size_t)k*NOUT + c] : 0.f;
  if(scale) v *= scale[c];
  int pk = kbase + k;
  out[(size_t)(pk >> 3)*NOUT*8 + (size_t)c*8 + (pk & 7)] = (ushort16)f2bf(v);
}

__global__ __launch_bounds__(256) void pack_all(const float* __restrict__ w_in, const float* __restrict__ w_gcn,
    const float* __restrict__ w_gat, const float* __restrict__ w_sl, const float* __restrict__ w_sr,
    const float* __restrict__ w_res,
    const float* __restrict__ s1, const float* __restrict__ s2, const float* __restrict__ s3,
    ushort16* __restrict__ pw_in, ushort16* __restrict__ pw_gcn,
    ushort16* __restrict__ pw_gat, ushort16* __restrict__ pw_cat){
  int b = blockIdx.x, t = threadIdx.x;
  if(b < 96)       pack_region(w_in,  165, 128, 0,   b*256 + t,        nullptr, pw_in);
  else if(b < 160) pack_region(w_gcn, 128, 128, 0,   (b-96)*256 + t,   s1,      pw_gcn);
  else if(b < 224) pack_region(w_gat, 128, 128, 0,   (b-160)*256 + t,  s2,      pw_gat);
  else if(b < 256) pack_region(w_sl,  128, 64,  0,   (b-224)*256 + t,  s3,      pw_cat);
  else if(b < 288) pack_region(w_sr,  128, 64,  128, (b-256)*256 + t,  s3,      pw_cat);
  else             pack_region(w_res, 128, 64,  256, (b-288)*256 + t,  nullptr, pw_cat);
}

// ---------------- MFMA bf16 GEMM ----------------
// EPI: 0 raw->bf16, 1 bias+elu->bf16, 3 raw->bf16 + fused GAT attention epilogue,
//      4 row-scale by dinv[r] -> bf16 (GCN fold)

template<int KSTEPS, int NOUT, int EPI>
__global__ __launch_bounds__(256) void mfma_gemm(
    const ushort16* __restrict__ A, int lda,
    const uint4v* __restrict__ pw,
    const float* __restrict__ bias,
    void* __restrict__ out, int ldo, int N,
    const float* __restrict__ dinv,
    const float* __restrict__ atts2, const float* __restrict__ attd2,
    float* __restrict__ a_src, float* __restrict__ a_dst,
    float* __restrict__ ess, uint32* __restrict__ Mint)
{
  constexpr int LDSV = KSTEPS*4*NOUT;
  __shared__ uint4v wlds[LDSV];
  int t = threadIdx.x;
#pragma unroll
  for(int q = 0; q < LDSV/256; q++)
    wlds[q*256 + t] = pw[q*256 + t];
  __syncthreads();

  int wid = t >> 6, lane = t & 63;
  int wm, wn;
  if(NOUT == 128){ wm = wid >> 1; wn = wid & 1; } else { wm = wid; wn = 0; }
  constexpr int MTILE = (NOUT == 128) ? 128 : 256;
  long row0 = (long)blockIdx.x*MTILE + wm*64;
  int l15 = lane & 15, lk = lane >> 4;
  int wn64 = wn*64;
  const ushort16* wl = (const ushort16*)wlds;

  float4v acc[4][4];
#pragma unroll
  for(int fm = 0; fm < 4; fm++)
#pragma unroll
    for(int fn = 0; fn < 4; fn++) acc[fm][fn] = (float4v){0.f,0.f,0.f,0.f};

  const ushort16* abase[4];
#pragma unroll
  for(int fm = 0; fm < 4; fm++){
    long r = row0 + fm*16 + l15;
    if(r > (long)N - 1) r = (long)N - 1;
    abase[fm] = A + r*(size_t)lda + lk*8;
  }

  short8v a[4];
#pragma unroll
  for(int fm = 0; fm < 4; fm++) a[fm] = *(const short8v*)(abase[fm]);

#pragma unroll
  for(int ks = 0; ks < KSTEPS; ks++){
    short8v b[4];
#pragma unroll
    for(int fn = 0; fn < 4; fn++){
      int c = wn64 + fn*16 + l15;
      b[fn] = *(const short8v*)(wl + ((size_t)((ks*4 + lk)*NOUT + c))*8);
    }
    short8v an[4];
    if(ks + 1 < KSTEPS){
#pragma unroll
      for(int fm = 0; fm < 4; fm++) an[fm] = *(const short8v*)(abase[fm] + (ks + 1)*32);
    }
#pragma unroll
    for(int fm = 0; fm < 4; fm++)
#pragma unroll
      for(int fn = 0; fn < 4; fn++)
        acc[fm][fn] = __builtin_amdgcn_mfma_f32_16x16x32_bf16(a[fm], b[fn], acc[fm][fn], 0, 0, 0);
    if(ks + 1 < KSTEPS){
#pragma unroll
      for(int fm = 0; fm < 4; fm++) a[fm] = an[fm];
    }
  }

  // C/D layout: col = lane&15, row = (lane>>4)*4 + reg
#pragma unroll
  for(int fm = 0; fm < 4; fm++){
#pragma unroll
    for(int rr = 0; rr < 4; rr++){
      long r = row0 + fm*16 + lk*4 + rr;
      if(r < N){
        float dr = 0.f;
        if constexpr(EPI == 4) dr = dinv[r];
#pragma unroll
        for(int fn = 0; fn < 4; fn++){
          int c = wn64 + fn*16 + l15;
          float v = acc[fm][fn][rr];
          if constexpr(EPI == 1){ v += bias[c]; v = elu_f(v); }
          if constexpr(EPI == 4){ v *= dr; }
          ((ushort16*)out)[r*(size_t)ldo + c] = (ushort16)f2bf(v);
        }
      }
    }
  }

  if constexpr(EPI == 3){
    // fused GAT attention scalars: wn selects head (cols 0-63 = head0, 64-127 = head1)
    float as2[4], ad2[4];
#pragma unroll
    for(int fn = 0; fn < 4; fn++){
      int c = wn64 + fn*16 + l15;
      as2[fn] = atts2[c]; ad2[fn] = attd2[c];
    }
#pragma unroll
    for(int fm = 0; fm < 4; fm++){
#pragma unroll
      for(int rr = 0; rr < 4; rr++){
        float p1 = 0.f, p2 = 0.f;
#pragma unroll
        for(int fn = 0; fn < 4; fn++){
          p1 += acc[fm][fn][rr]*as2[fn];
          p2 += acc[fm][fn][rr]*ad2[fn];
        }
#pragma unroll
        for(int o = 1; o < 16; o <<= 1){
          p1 += __shfl_xor(p1, o);
          p2 += __shfl_xor(p2, o);
        }
        long r = row0 + fm*16 + lk*4 + rr;
        if(l15 == 0 && r < N){
          a_src[2*r + wn] = p1;
          a_dst[2*r + wn] = p2;
          float es = leaky_f(p1 + p2);
          ess[2*r + wn] = es;
          Mint[2*r + wn] = fenc(es);
        }
      }
    }
  }
}

// ---------------- GCN aggregation (dinv pre-folded) + BN1 + ELU ----------------

__global__ __launch_bounds__(256) void gcn_agg(const uint32* __restrict__ hw2,   // stride 64 uints
    const int* __restrict__ rowptr, const int* __restrict__ col,
    const float* __restrict__ dinv, const float* __restrict__ b1c,
    uint32* __restrict__ h1, int N)
{
  int t = threadIdx.x & 63;
  int w = __builtin_amdgcn_readfirstlane(threadIdx.x >> 6);
  float2 bc = ((const float2*)b1c)[t];
  int stride = gridDim.x*4;
  for(int i = blockIdx.x*4 + w; i < N; i += stride){
    int beg = rowptr[i], end = rowptr[i+1];
    float di = dinv[i];
    uint32 su = hw2[(size_t)i*64 + t];
    float a0 = bflo(su), a1 = bfhi(su);    // self loop (hw2 already has dinv folded)
#define GCN_ROW(q) { int row = __builtin_amdgcn_readlane(s, q); \
    uint32 u = hw2[(size_t)row*64 + t]; a0 += bflo(u); a1 += bfhi(u); }
    for(int c0 = beg; c0 < end; c0 += 64){
      int p = c0 + t;
      int cl = end - c0; if(cl > 64) cl = 64;
      int s = (p < end) ? col[p] : 0;
      int q = 0;
      for(; q + 4 <= cl; q += 4){ GCN_ROW(q) GCN_ROW(q+1) GCN_ROW(q+2) GCN_ROW(q+3) }
      for(; q < cl; q++){ GCN_ROW(q) }
    }
#undef GCN_ROW
    float v0 = a0*di + bc.x;
    float v1 = a1*di + bc.y;
    h1[(size_t)i*64 + t] = f2bf(elu_f(v0)) | (f2bf(elu_f(v1)) << 16);
  }
}

// ---------------- per-edge logits + segment max (deterministic atomicMax) ----------------

__global__ void edge_logit(const int* __restrict__ src, const int* __restrict__ dst,
                           const int* __restrict__ pos, int E,
                           const float* __restrict__ a_src, const float* __restrict__ a_dst,
                           float2* __restrict__ lcsr, uint32* __restrict__ Mint){
  int i = blockIdx.x*blockDim.x + threadIdx.x;
  if(i >= E) return;
  int s = src[i], d = dst[i], p = pos[i];
  float2 as = ((const float2*)a_src)[s];
  float2 ad = ((const float2*)a_dst)[d];
  float l0 = leaky_f(as.x + ad.x);
  float l1 = leaky_f(as.y + ad.y);
  lcsr[p] = make_float2(l0, l1);
  atomicMax(&Mint[2*d],   fenc(l0));
  atomicMax(&Mint[2*d+1], fenc(l1));
}

// ---------------- GAT gather: exp + denom + weighted sum + folded BN2 + ELU ----------------
// writes h2 (bf16) into Acat[:,128:256]  (out pre-offset, stride 192 uints)

__global__ __launch_bounds__(256) void gat_gather(const uint32* __restrict__ g,   // stride 64
    const int* __restrict__ rowptr, const int* __restrict__ col,
    const float2* __restrict__ lcsr, const uint32* __restrict__ Mint, const float* __restrict__ ess,
    const float* __restrict__ b2c, uint32* __restrict__ h2out, int N)
{
  int t = threadIdx.x & 63;
  int w = __builtin_amdgcn_readfirstlane(threadIdx.x >> 6);
  float2 bc = ((const float2*)b2c)[t];
  int hl = t >> 5;
  int stride = gridDim.x*4;
  for(int i = blockIdx.x*4 + w; i < N; i += stride){
    int beg = rowptr[i], end = rowptr[i+1];
    float M0 = fdec(Mint[2*i]), M1 = fdec(Mint[2*i+1]);
    float es0 = ess[2*i], es1 = ess[2*i+1];
    float d0 = 0.f, d1 = 0.f, a0 = 0.f, a1 = 0.f;
#define GAT_ROW(q) { int row = __builtin_amdgcn_readlane(s, q); \
    float w0q = readlane_f(e0, q); \
    float w1q = readlane_f(e1, q); \
    float wq = hl ? w1q : w0q; \
    uint32 u = g[(size_t)row*64 + t]; a0 += wq*bflo(u); a1 += wq*bfhi(u); }
    for(int c0 = beg; c0 < end; c0 += 64){
      int p = c0 + t;
      int cl = end - c0; if(cl > 64) cl = 64;
      float e0 = 0.f, e1 = 0.f; int s = 0;
      if(p < end){
        float2 l = lcsr[p];
        e0 = __expf(l.x - M0); e1 = __expf(l.y - M1);
        s = col[p];
      }
      d0 += e0; d1 += e1;
      int q = 0;
      for(; q + 4 <= cl; q += 4){ GAT_ROW(q) GAT_ROW(q+1) GAT_ROW(q+2) GAT_ROW(q+3) }
      for(; q < cl; q++){ GAT_ROW(q) }
    }
#undef GAT_ROW
#pragma unroll
    for(int o = 32; o > 0; o >>= 1){ d0 += __shfl_xor(d0, o); d1 += __shfl_xor(d1, o); }
    float sw0 = __expf(es0 - M0), sw1 = __expf(es1 - M1);
    float rD = 1.f/(((hl ? d1 : d0) + (hl ? sw1 : sw0)) + 1e-16f);
    float sw = hl ? sw1 : sw0;
    uint32 su = g[(size_t)i*64 + t];
    float v0 = (a0 + sw*bflo(su))*rD + bc.x;
    float v1 = (a1 + sw*bfhi(su))*rD + bc.y;
    h2out[(size_t)i*192 + t] = f2bf(elu_f(v0)) | (f2bf(elu_f(v1)) << 16);
  }
}

// ---------------- SAGE mean (no self loops), inside Acat ----------------

__global__ __launch_bounds__(256) void sage_mean(const uint32* __restrict__ h2,  // pre-offset +64, stride 192
    const int* __restrict__ rowptr, const int* __restrict__ col,
    uint32* __restrict__ mout, int N)                                             // stride 192
{
  int t = threadIdx.x & 63;
  int w = __builtin_amdgcn_readfirstlane(threadIdx.x >> 6);
  int stride = gridDim.x*4;
  for(int i = blockIdx.x*4 + w; i < N; i += stride){
    int beg = rowptr[i], end = rowptr[i+1];
    float a0 = 0.f, a1 = 0.f;
#define SAGE_ROW(q) { int row = __builtin_amdgcn_readlane(s, q); \
    uint32 u = h2[(size_t)row*192 + t]; a0 += bflo(u); a1 += bfhi(u); }
    for(int c0 = beg; c0 < end; c0 += 64){
      int p = c0 + t;
      int cl = end - c0; if(cl > 64) cl = 64;
      int s = (p < end) ? col[p] : 0;
      int q = 0;
      for(; q + 4 <= cl; q += 4){ SAGE_ROW(q) SAGE_ROW(q+1) SAGE_ROW(q+2) SAGE_ROW(q+3) }
      for(; q < cl; q++){ SAGE_ROW(q) }
    }
#undef SAGE_ROW
    float inv = 1.f/fmaxf((float)(end - beg), 1.f);
    mout[(size_t)i*192 + t] = f2bf(a0*inv) | (f2bf(a1*inv) << 16);
  }
}

// ---------------- classifier: out = elu(h3@w1+b1)@w2 + b2  (h3 bf16) ----------------

__global__ __launch_bounds__(256) void classifier_kernel(const uint32* __restrict__ h3,  // stride 32 uints
    const float* __restrict__ w1, const float* __restrict__ b1,
    const float* __restrict__ w2, const float* __restrict__ b2,
    float* __restrict__ out, int N)
{
  __shared__ float hs[8][64];
  __shared__ float zs[8][32];
  int node0 = blockIdx.x*8;
  int t = threadIdx.x;
  {
    int r = t >> 5, cp = t & 31;
    int nd = node0 + r;
    uint32 u = (nd < N) ? h3[(size_t)nd*32 + cp] : 0u;
    hs[r][2*cp]   = bflo(u);
    hs[r][2*cp+1] = bfhi(u);
  }
  __syncthreads();
  int nn = t >> 5, ln = t & 31;
  float acc = b1[ln];
#pragma unroll
  for(int k = 0; k < 64; k++) acc += hs[nn][k]*w1[k*32 + ln];
  zs[nn][ln] = elu_f(acc);
  __syncthreads();
  int node = node0 + nn;
  if(ln < 2 && node < N){
    float o = b2[ln];
#pragma unroll
    for(int k = 0; k < 32; k++) o += zs[nn][k]*w2[k*2 + ln];
    out[(size_t)node*2 + ln] = o;
  }
}

// ---------------- launch ----------------

extern "C" void kernel_launch(void* const* d_in, const int* in_sizes, int n_in,
                              void* d_out, int out_size, void* d_ws, size_t ws_size,
                              hipStream_t stream)
{
  (void)n_in; (void)out_size; (void)ws_size;
  const float* x      = (const float*)d_in[0];
  const int*   ei     = (const int*)  d_in[1];
  const float* w_in   = (const float*)d_in[2];
  const float* b_in   = (const float*)d_in[3];
  const float* w_gcn  = (const float*)d_in[4];
  const float* b_gcn  = (const float*)d_in[5];
  const float* bn1_g  = (const float*)d_in[6];
  const float* bn1_b  = (const float*)d_in[7];
  const float* bn1_m  = (const float*)d_in[8];
  const float* bn1_v  = (const float*)d_in[9];
  const float* w_gat  = (const float*)d_in[10];
  const float* att_s  = (const float*)d_in[11];
  const float* att_d  = (const float*)d_in[12];
  const float* b_gat  = (const float*)d_in[13];
  const float* bn2_g  = (const float*)d_in[14];
  const float* bn2_b  = (const float*)d_in[15];
  const float* bn2_m  = (const float*)d_in[16];
  const float* bn2_v  = (const float*)d_in[17];
  const float* w_sl   = (const float*)d_in[18];
  const float* b_sage = (const float*)d_in[19];
  const float* w_sr   = (const float*)d_in[20];
  const float* bn3_g  = (const float*)d_in[21];
  const float* bn3_b  = (const float*)d_in[22];
  const float* bn3_m  = (const float*)d_in[23];
  const float* bn3_v  = (const float*)d_in[24];
  const float* w_res  = (const float*)d_in[25];
  const float* b_res  = (const float*)d_in[26];
  const float* w_c1   = (const float*)d_in[27];
  const float* b_c1   = (const float*)d_in[28];
  const float* w_c2   = (const float*)d_in[29];
  const float* b_c2   = (const float*)d_in[30];

  const int F_IN = 165;
  int N = in_sizes[0]/F_IN;
  int E = in_sizes[1]/2;
  const int* srcp = ei;
  const int* dstp = ei + E;
  int nb = (N + 1023) >> 10;

  char* p = (char*)d_ws;
  auto alloc = [&](size_t bytes) -> char* {
    char* q = p; p += (bytes + 255) & ~(size_t)255; return q;
  };
  ushort16* Acat  = (ushort16*)alloc((size_t)N*384*2);   // [mean_nb | h2 | h]
  ushort16* xb    = (ushort16*)alloc((size_t)N*192*2);   // later reused for h1
  ushort16* bufG  = (ushort16*)alloc((size_t)N*128*2);   // hw2 -> g -> h3(bf16)
  float* a_src    = (float*)alloc((size_t)N*2*4);
  float* a_dst    = (float*)alloc((size_t)N*2*4);
  float* ess      = (float*)alloc((size_t)N*2*4);
  uint32* Mint    = (uint32*)alloc((size_t)N*2*4);
  float* dinv     = (float*)alloc((size_t)N*4);
  int* cnt        = (int*)alloc((size_t)N*4);
  int* fill       = (int*)alloc((size_t)N*4);
  int* rowptr     = (int*)alloc((size_t)(N+1)*4);
  int* part       = (int*)alloc((size_t)N*4);
  int* bsum       = (int*)alloc(1024*4);
  int* boff       = (int*)alloc(1024*4);
  int* col        = (int*)alloc((size_t)E*4);
  int* pos        = (int*)alloc((size_t)E*4);
  float2* lcsr    = (float2*)alloc((size_t)E*8);
  float* s1       = (float*)alloc(128*4);
  float* b1c      = (float*)alloc(128*4);
  float* s2       = (float*)alloc(128*4);
  float* b2c      = (float*)alloc(128*4);
  float* atts2    = (float*)alloc(128*4);
  float* attd2    = (float*)alloc(128*4);
  float* s3       = (float*)alloc(64*4);
  float* bias3    = (float*)alloc(64*4);
  ushort16* pw_in  = (ushort16*)alloc(6*4*128*16);   // 48 KB
  ushort16* pw_gcn = (ushort16*)alloc(4*4*128*16);   // 32 KB
  ushort16* pw_gat = (ushort16*)alloc(4*4*128*16);
  ushort16* pw_cat = (ushort16*)alloc(12*4*64*16);   // 48 KB

  ushort16* h1 = xb;                 // xb dead after GEMM1
  ushort16* h3 = bufG;               // g dead after gat_gather

  // cnt and fill are adjacent allocations: one memset covers both (incl. pad)
  hipMemsetAsync(cnt, 0, (size_t)((char*)(fill + N) - (char*)cnt), stream);

  count_deg_kernel<<<(E+255)/256, 256, 0, stream>>>(dstp, E, cnt);
  scan_blocks<<<nb, 1024, 0, stream>>>(cnt, N, part, bsum);
  scan_bsum<<<1, 1024, 0, stream>>>(bsum, nb, boff, rowptr, N);
  scan_add_dinv<<<(N+255)/256, 256, 0, stream>>>(part, boff, cnt, N, rowptr, dinv);
  scatter_kernel<<<(E+255)/256, 256, 0, stream>>>(srcp, dstp, E, rowptr, fill, col, pos);

  cvt_x<<<(N*48 + 255)/256, 256, 0, stream>>>(x, (uint2*)xb, N*48);
  prep_scales<<<1, 128, 0, stream>>>(bn1_g, bn1_b, bn1_m, bn1_v, b_gcn,
                                     bn2_g, bn2_b, bn2_m, bn2_v, b_gat,
                                     att_s, att_d,
                                     bn3_g, bn3_b, bn3_m, bn3_v, b_sage, b_res,
                                     s1, b1c, s2, b2c, atts2, attd2, s3, bias3);
  pack_all<<<320, 256, 0, stream>>>(w_in, w_gcn, w_gat, w_sl, w_sr, w_res,
                                    s1, s2, s3, pw_in, pw_gcn, pw_gat, pw_cat);

  int g128 = (N + 127)/128;
  int g256 = (N + 255)/256;
  int gagg = (N + 3)/4; if(gagg > 4096) gagg = 4096;

  // h = elu(x@w_in + b_in)  -> Acat[:,256:384]
  mfma_gemm<6,128,1><<<g128, 256, 0, stream>>>(xb, 192, (const uint4v*)pw_in, b_in,
      (void*)(Acat + 256), 384, N, nullptr, nullptr, nullptr, nullptr, nullptr, nullptr, nullptr);
  // hw2 = (h@(w_gcn*s1))*dinv[row] -> bufG
  mfma_gemm<4,128,4><<<g128, 256, 0, stream>>>(Acat + 256, 384, (const uint4v*)pw_gcn, nullptr,
      (void*)bufG, 128, N, dinv, nullptr, nullptr, nullptr, nullptr, nullptr, nullptr);
  // h1 = elu(sum(hw2)*di + b1c)
  gcn_agg<<<gagg, 256, 0, stream>>>((const uint32*)bufG, rowptr, col, dinv, b1c,
                                    (uint32*)h1, N);
  // g' = h1@(w_gat*s2) -> bufG, + fused attention scalars / self logits / M init
  mfma_gemm<4,128,3><<<g128, 256, 0, stream>>>(h1, 128, (const uint4v*)pw_gat, nullptr,
      (void*)bufG, 128, N, nullptr, atts2, attd2, a_src, a_dst, ess, Mint);
  // per-edge logits + segment max
  edge_logit<<<(E+255)/256, 256, 0, stream>>>(srcp, dstp, pos, E, a_src, a_dst, lcsr, Mint);
  // h2 -> Acat[:,128:256]
  gat_gather<<<gagg, 256, 0, stream>>>((const uint32*)bufG, rowptr, col, lcsr, Mint, ess,
                                       b2c, (uint32*)Acat + 64, N);
  // mean_nb -> Acat[:,0:128]
  sage_mean<<<gagg, 256, 0, stream>>>((const uint32*)Acat + 64, rowptr, col, (uint32*)Acat, N);
  // h3 = elu((Acat @ [w_sl*s3; w_sr*s3; w_res]) + bias3) -> bf16
  mfma_gemm<12,64,1><<<g256, 256, 0, stream>>>(Acat, 384, (const uint4v*)pw_cat, bias3,
      (void*)h3, 64, N, nullptr, nullptr, nullptr, nullptr, nullptr, nullptr, nullptr);
  classifier_kernel<<<(N+7)/8, 256, 0, stream>>>((const uint32*)h3, w_c1, b_c1, w_c2, b_c2,
                                                 (float*)d_out, N);
}

// Round 8
// 336.797 us; speedup vs baseline: 1.5403x; 1.1233x over previous
//
#include <hip/hip_runtime.h>
#include <cstdint>
#include <cstddef>

#define BN_EPS 1e-5f

typedef __attribute__((ext_vector_type(8))) short short8v;
typedef __attribute__((ext_vector_type(4))) float float4v;
typedef __attribute__((ext_vector_type(4))) unsigned int uint4v;
typedef unsigned int uint32;
typedef unsigned short ushort16;

__device__ __forceinline__ float elu_f(float v){ return v > 0.f ? v : expm1f(v); }
__device__ __forceinline__ float leaky_f(float v){ return v > 0.f ? v : 0.2f*v; }
__device__ __forceinline__ uint32 f2bf(float f){
  uint32 b = __float_as_uint(f);
  return (b + 0x7fffu + ((b >> 16) & 1u)) >> 16;        // RNE
}
__device__ __forceinline__ float bflo(uint32 u){ return __uint_as_float(u << 16); }
__device__ __forceinline__ float bfhi(uint32 u){ return __uint_as_float(u & 0xffff0000u); }
__device__ __forceinline__ float readlane_f(float v, int l){
  return __int_as_float(__builtin_amdgcn_readlane(__float_as_int(v), l));
}

// ---------------- graph preprocessing: CSR by dst ----------------

__global__ void count_deg_kernel(const int* __restrict__ dst, int E, int* __restrict__ cnt){
  int i = blockIdx.x*blockDim.x + threadIdx.x;
  if(i < E) atomicAdd(&cnt[dst[i]], 1);
}

__global__ __launch_bounds__(1024) void scan_blocks(const int* __restrict__ cnt, int n,
                                                    int* __restrict__ part, int* __restrict__ bsum){
  __shared__ int wsum[16];
  int tid = threadIdx.x, lane = tid & 63, w = tid >> 6;
  int i = blockIdx.x*1024 + tid;
  int v = (i < n) ? cnt[i] : 0;
  int sv = v;
#pragma unroll
  for(int o = 1; o < 64; o <<= 1){
    int u = __shfl_up(sv, o);
    if(lane >= o) sv += u;
  }
  if(lane == 63) wsum[w] = sv;
  __syncthreads();
  int woff = 0;
#pragma unroll
  for(int q = 0; q < 16; q++) woff += (q < w) ? wsum[q] : 0;
  if(i < n) part[i] = woff + sv - v;
  if(tid == 1023) bsum[blockIdx.x] = woff + sv;
}

__global__ __launch_bounds__(1024) void scan_bsum(const int* __restrict__ bsum, int nb,
                                                  int* __restrict__ boff, int* __restrict__ rowptr, int n){
  __shared__ int wsum[16];
  int tid = threadIdx.x, lane = tid & 63, w = tid >> 6;
  int v = (tid < nb) ? bsum[tid] : 0;
  int sv = v;
#pragma unroll
  for(int o = 1; o < 64; o <<= 1){
    int u = __shfl_up(sv, o);
    if(lane >= o) sv += u;
  }
  if(lane == 63) wsum[w] = sv;
  __syncthreads();
  int woff = 0;
#pragma unroll
  for(int q = 0; q < 16; q++) woff += (q < w) ? wsum[q] : 0;
  if(tid < nb) boff[tid] = woff + sv - v;
  if(tid == 1023) rowptr[n] = woff + sv;
}

__global__ void scan_add_dinv(const int* __restrict__ part, const int* __restrict__ boff,
                              const int* __restrict__ cnt, int n,
                              int* __restrict__ rowptr, float* __restrict__ dinv){
  int i = blockIdx.x*blockDim.x + threadIdx.x;
  if(i < n){
    rowptr[i] = part[i] + boff[i >> 10];
    dinv[i] = rsqrtf((float)cnt[i] + 1.0f);   // deg includes self loop
  }
}

__global__ void scatter_kernel(const int* __restrict__ src, const int* __restrict__ dst, int E,
                               const int* __restrict__ rowptr, int* __restrict__ fill,
                               int* __restrict__ col){
  int i = blockIdx.x*blockDim.x + threadIdx.x;
  if(i < E){
    int s = src[i], d = dst[i];
    int p = rowptr[d] + atomicAdd(&fill[d], 1);
    col[p] = s;
  }
}

// ---------------- x -> bf16, K padded 165 -> 192, uint2 writes ----------------

__global__ __launch_bounds__(256) void cvt_x(const float* __restrict__ x, uint2* __restrict__ xb, int total){
  int idx = blockIdx.x*256 + threadIdx.x;     // over N*48 uint2
  if(idx >= total) return;
  int row = idx/48;
  int cp = idx - row*48;
  int c = cp*4;
  const float* xr = x + (size_t)row*165;
  float v0 = (c   < 165) ? xr[c]   : 0.f;
  float v1 = (c+1 < 165) ? xr[c+1] : 0.f;
  float v2 = (c+2 < 165) ? xr[c+2] : 0.f;
  float v3 = (c+3 < 165) ? xr[c+3] : 0.f;
  xb[idx] = make_uint2(f2bf(v0) | (f2bf(v1) << 16), f2bf(v2) | (f2bf(v3) << 16));
}

// ---------------- BN folding: per-channel scales + combined biases ----------------

__global__ void prep_scales(const float* __restrict__ bn1_g, const float* __restrict__ bn1_b,
    const float* __restrict__ bn1_m, const float* __restrict__ bn1_v, const float* __restrict__ b_gcn,
    const float* __restrict__ bn2_g, const float* __restrict__ bn2_b,
    const float* __restrict__ bn2_m, const float* __restrict__ bn2_v, const float* __restrict__ b_gat,
    const float* __restrict__ att_s, const float* __restrict__ att_d,
    const float* __restrict__ bn3_g, const float* __restrict__ bn3_b,
    const float* __restrict__ bn3_m, const float* __restrict__ bn3_v,
    const float* __restrict__ b_sage, const float* __restrict__ b_res,
    float* __restrict__ s1, float* __restrict__ b1c,
    float* __restrict__ s2, float* __restrict__ b2c,
    float* __restrict__ atts2, float* __restrict__ attd2,
    float* __restrict__ s3, float* __restrict__ bias3){
  int c = threadIdx.x;   // 128
  float v1 = bn1_g[c]*rsqrtf(bn1_v[c] + BN_EPS);
  s1[c] = v1;
  b1c[c] = (b_gcn[c] - bn1_m[c])*v1 + bn1_b[c];
  float v2 = bn2_g[c]*rsqrtf(bn2_v[c] + BN_EPS);
  s2[c] = v2;
  b2c[c] = (b_gat[c] - bn2_m[c])*v2 + bn2_b[c];
  atts2[c] = att_s[c]/v2;
  attd2[c] = att_d[c]/v2;
  if(c < 64){
    float v3 = bn3_g[c]*rsqrtf(bn3_v[c] + BN_EPS);
    s3[c] = v3;
    bias3[c] = (b_sage[c] - bn3_m[c])*v3 + bn3_b[c] + b_res[c];
  }
}

// ---------------- weight packing (one launch): packed[kgrp][col][8] bf16 ----------------

__device__ __forceinline__ void pack_region(const float* __restrict__ W, int K, int NOUT, int kbase, int idx,
                                            const float* __restrict__ scale, ushort16* __restrict__ out){
  int k = idx / NOUT, c = idx - k*NOUT;
  float v = (k < K) ? W[(size_t)k*NOUT + c] : 0.f;
  if(scale) v *= scale[c];
  int pk = kbase + k;
  out[(size_t)(pk >> 3)*NOUT*8 + (size_t)c*8 + (pk & 7)] = (ushort16)f2bf(v);
}

__global__ __launch_bounds__(256) void pack_all(const float* __restrict__ w_in, const float* __restrict__ w_gcn,
    const float* __restrict__ w_gat, const float* __restrict__ w_sl, const float* __restrict__ w_sr,
    const float* __restrict__ w_res,
    const float* __restrict__ s1, const float* __restrict__ s2, const float* __restrict__ s3,
    ushort16* __restrict__ pw_in, ushort16* __restrict__ pw_gcn,
    ushort16* __restrict__ pw_gat, ushort16* __restrict__ pw_cat){
  int b = blockIdx.x, t = threadIdx.x;
  if(b < 96)       pack_region(w_in,  165, 128, 0,   b*256 + t,        nullptr, pw_in);
  else if(b < 160) pack_region(w_gcn, 128, 128, 0,   (b-96)*256 + t,   s1,      pw_gcn);
  else if(b < 224) pack_region(w_gat, 128, 128, 0,   (b-160)*256 + t,  s2,      pw_gat);
  else if(b < 256) pack_region(w_sl,  128, 64,  0,   (b-224)*256 + t,  s3,      pw_cat);
  else if(b < 288) pack_region(w_sr,  128, 64,  128, (b-256)*256 + t,  s3,      pw_cat);
  else             pack_region(w_res, 128, 64,  256, (b-288)*256 + t,  nullptr, pw_cat);
}

// ---------------- MFMA bf16 GEMM ----------------
// EPI: 0 raw->bf16, 1 bias+elu->bf16, 3 raw->bf16 + fused GAT attention epilogue,
//      4 row-scale by dinv[r] -> bf16 (GCN fold)

template<int KSTEPS, int NOUT, int EPI>
__global__ __launch_bounds__(256) void mfma_gemm(
    const ushort16* __restrict__ A, int lda,
    const uint4v* __restrict__ pw,
    const float* __restrict__ bias,
    void* __restrict__ out, int ldo, int N,
    const float* __restrict__ dinv,
    const float* __restrict__ atts2, const float* __restrict__ attd2,
    float* __restrict__ a_src, float* __restrict__ a_dst,
    float* __restrict__ ess)
{
  constexpr int LDSV = KSTEPS*4*NOUT;
  __shared__ uint4v wlds[LDSV];
  int t = threadIdx.x;
#pragma unroll
  for(int q = 0; q < LDSV/256; q++)
    wlds[q*256 + t] = pw[q*256 + t];
  __syncthreads();

  int wid = t >> 6, lane = t & 63;
  int wm, wn;
  if(NOUT == 128){ wm = wid >> 1; wn = wid & 1; } else { wm = wid; wn = 0; }
  constexpr int MTILE = (NOUT == 128) ? 128 : 256;
  long row0 = (long)blockIdx.x*MTILE + wm*64;
  int l15 = lane & 15, lk = lane >> 4;
  int wn64 = wn*64;
  const ushort16* wl = (const ushort16*)wlds;

  float4v acc[4][4];
#pragma unroll
  for(int fm = 0; fm < 4; fm++)
#pragma unroll
    for(int fn = 0; fn < 4; fn++) acc[fm][fn] = (float4v){0.f,0.f,0.f,0.f};

  const ushort16* abase[4];
#pragma unroll
  for(int fm = 0; fm < 4; fm++){
    long r = row0 + fm*16 + l15;
    if(r > (long)N - 1) r = (long)N - 1;
    abase[fm] = A + r*(size_t)lda + lk*8;
  }

  short8v a[4];
#pragma unroll
  for(int fm = 0; fm < 4; fm++) a[fm] = *(const short8v*)(abase[fm]);

#pragma unroll
  for(int ks = 0; ks < KSTEPS; ks++){
    short8v b[4];
#pragma unroll
    for(int fn = 0; fn < 4; fn++){
      int c = wn64 + fn*16 + l15;
      b[fn] = *(const short8v*)(wl + ((size_t)((ks*4 + lk)*NOUT + c))*8);
    }
    short8v an[4];
    if(ks + 1 < KSTEPS){
#pragma unroll
      for(int fm = 0; fm < 4; fm++) an[fm] = *(const short8v*)(abase[fm] + (ks + 1)*32);
    }
#pragma unroll
    for(int fm = 0; fm < 4; fm++)
#pragma unroll
      for(int fn = 0; fn < 4; fn++)
        acc[fm][fn] = __builtin_amdgcn_mfma_f32_16x16x32_bf16(a[fm], b[fn], acc[fm][fn], 0, 0, 0);
    if(ks + 1 < KSTEPS){
#pragma unroll
      for(int fm = 0; fm < 4; fm++) a[fm] = an[fm];
    }
  }

  // C/D layout: col = lane&15, row = (lane>>4)*4 + reg
#pragma unroll
  for(int fm = 0; fm < 4; fm++){
#pragma unroll
    for(int rr = 0; rr < 4; rr++){
      long r = row0 + fm*16 + lk*4 + rr;
      if(r < N){
        float dr = 0.f;
        if constexpr(EPI == 4) dr = dinv[r];
#pragma unroll
        for(int fn = 0; fn < 4; fn++){
          int c = wn64 + fn*16 + l15;
          float v = acc[fm][fn][rr];
          if constexpr(EPI == 1){ v += bias[c]; v = elu_f(v); }
          if constexpr(EPI == 4){ v *= dr; }
          ((ushort16*)out)[r*(size_t)ldo + c] = (ushort16)f2bf(v);
        }
      }
    }
  }

  if constexpr(EPI == 3){
    // fused GAT attention scalars: wn selects head (cols 0-63 = head0, 64-127 = head1)
    float as2[4], ad2[4];
#pragma unroll
    for(int fn = 0; fn < 4; fn++){
      int c = wn64 + fn*16 + l15;
      as2[fn] = atts2[c]; ad2[fn] = attd2[c];
    }
#pragma unroll
    for(int fm = 0; fm < 4; fm++){
#pragma unroll
      for(int rr = 0; rr < 4; rr++){
        float p1 = 0.f, p2 = 0.f;
#pragma unroll
        for(int fn = 0; fn < 4; fn++){
          p1 += acc[fm][fn][rr]*as2[fn];
          p2 += acc[fm][fn][rr]*ad2[fn];
        }
#pragma unroll
        for(int o = 1; o < 16; o <<= 1){
          p1 += __shfl_xor(p1, o);
          p2 += __shfl_xor(p2, o);
        }
        long r = row0 + fm*16 + lk*4 + rr;
        if(l15 == 0 && r < N){
          a_src[2*r + wn] = p1;
          a_dst[2*r + wn] = p2;
          ess[2*r + wn] = leaky_f(p1 + p2);
        }
      }
    }
  }
}

// ---------------- GCN aggregation (dinv pre-folded) + BN1 + ELU ----------------

__global__ __launch_bounds__(256) void gcn_agg(const uint32* __restrict__ hw2,   // stride 64 uints
    const int* __restrict__ rowptr, const int* __restrict__ col,
    const float* __restrict__ dinv, const float* __restrict__ b1c,
    uint32* __restrict__ h1, int N)
{
  int t = threadIdx.x & 63;
  int w = __builtin_amdgcn_readfirstlane(threadIdx.x >> 6);
  float2 bc = ((const float2*)b1c)[t];
  int stride = gridDim.x*4;
  for(int i = blockIdx.x*4 + w; i < N; i += stride){
    int beg = rowptr[i], end = rowptr[i+1];
    float di = dinv[i];
    uint32 su = hw2[(size_t)i*64 + t];
    float a0 = bflo(su), a1 = bfhi(su);    // self loop (hw2 already has dinv folded)
#define GCN_ROW(q) { int row = __builtin_amdgcn_readlane(s, q); \
    uint32 u = hw2[(size_t)row*64 + t]; a0 += bflo(u); a1 += bfhi(u); }
    for(int c0 = beg; c0 < end; c0 += 64){
      int p = c0 + t;
      int cl = end - c0; if(cl > 64) cl = 64;
      int s = (p < end) ? col[p] : 0;
      int q = 0;
      for(; q + 4 <= cl; q += 4){ GCN_ROW(q) GCN_ROW(q+1) GCN_ROW(q+2) GCN_ROW(q+3) }
      for(; q < cl; q++){ GCN_ROW(q) }
    }
#undef GCN_ROW
    float v0 = a0*di + bc.x;
    float v1 = a1*di + bc.y;
    h1[(size_t)i*64 + t] = f2bf(elu_f(v0)) | (f2bf(elu_f(v1)) << 16);
  }
}

// ---------------- GAT gather: in-register softmax + weighted sum + folded BN2 + ELU ----------
// writes h2 (bf16) into Acat[:,128:256]  (out pre-offset, stride 192 uints)

__global__ __launch_bounds__(256) void gat_gather(const uint32* __restrict__ g,   // stride 64
    const int* __restrict__ rowptr, const int* __restrict__ col,
    const float* __restrict__ a_src, const float* __restrict__ a_dst,
    const float* __restrict__ ess, const float* __restrict__ b2c,
    uint32* __restrict__ h2out, int N)
{
  int t = threadIdx.x & 63;
  int w = __builtin_amdgcn_readfirstlane(threadIdx.x >> 6);
  float2 bc = ((const float2*)b2c)[t];
  int hl = t >> 5;
  int stride = gridDim.x*4;
  for(int i = blockIdx.x*4 + w; i < N; i += stride){
    int beg = rowptr[i], end = rowptr[i+1];
    int deg = end - beg;
    float2 ad = ((const float2*)a_dst)[i];
    float es0 = ess[2*i], es1 = ess[2*i+1];    // self leaky-logits
    float d0 = 0.f, d1 = 0.f, a0 = 0.f, a1 = 0.f;
    float M0, M1;
#define GAT_ROWF(q) { int row = __builtin_amdgcn_readlane(s, q); \
    float w0q = readlane_f(e0, q); \
    float w1q = readlane_f(e1, q); \
    float wq = hl ? w1q : w0q; \
    uint32 u = g[(size_t)row*64 + t]; a0 += wq*bflo(u); a1 += wq*bfhi(u); }
    if(deg <= 64){
      // single chunk: logits live in registers, one gather of a_src per edge total
      int p = beg + t;
      int s = 0; float l0 = -3e38f, l1 = -3e38f;
      if(p < end){
        s = col[p];
        float2 as = ((const float2*)a_src)[s];
        l0 = leaky_f(as.x + ad.x);
        l1 = leaky_f(as.y + ad.y);
      }
      float m0 = fmaxf(l0, es0), m1 = fmaxf(l1, es1);
#pragma unroll
      for(int o = 32; o > 0; o >>= 1){ m0 = fmaxf(m0, __shfl_xor(m0, o)); m1 = fmaxf(m1, __shfl_xor(m1, o)); }
      M0 = m0; M1 = m1;
      float e0 = (p < end) ? __expf(l0 - M0) : 0.f;
      float e1 = (p < end) ? __expf(l1 - M1) : 0.f;
      d0 = e0; d1 = e1;
      int q = 0;
      for(; q + 4 <= deg; q += 4){ GAT_ROWF(q) GAT_ROWF(q+1) GAT_ROWF(q+2) GAT_ROWF(q+3) }
      for(; q < deg; q++){ GAT_ROWF(q) }
    } else {
      // generic: pass 1 max, pass 2 exp + gather
      float m0 = es0, m1 = es1;
      for(int p = beg + t; p < end; p += 64){
        float2 as = ((const float2*)a_src)[col[p]];
        m0 = fmaxf(m0, leaky_f(as.x + ad.x));
        m1 = fmaxf(m1, leaky_f(as.y + ad.y));
      }
#pragma unroll
      for(int o = 32; o > 0; o >>= 1){ m0 = fmaxf(m0, __shfl_xor(m0, o)); m1 = fmaxf(m1, __shfl_xor(m1, o)); }
      M0 = m0; M1 = m1;
      for(int c0 = beg; c0 < end; c0 += 64){
        int p = c0 + t;
        int cl = end - c0; if(cl > 64) cl = 64;
        float e0 = 0.f, e1 = 0.f; int s = 0;
        if(p < end){
          s = col[p];
          float2 as = ((const float2*)a_src)[s];
          e0 = __expf(leaky_f(as.x + ad.x) - M0);
          e1 = __expf(leaky_f(as.y + ad.y) - M1);
        }
        d0 += e0; d1 += e1;
        int q = 0;
        for(; q + 4 <= cl; q += 4){ GAT_ROWF(q) GAT_ROWF(q+1) GAT_ROWF(q+2) GAT_ROWF(q+3) }
        for(; q < cl; q++){ GAT_ROWF(q) }
      }
    }
#undef GAT_ROWF
#pragma unroll
    for(int o = 32; o > 0; o >>= 1){ d0 += __shfl_xor(d0, o); d1 += __shfl_xor(d1, o); }
    float sw0 = __expf(es0 - M0), sw1 = __expf(es1 - M1);
    float rD = 1.f/(((hl ? d1 : d0) + (hl ? sw1 : sw0)) + 1e-16f);
    float sw = hl ? sw1 : sw0;
    uint32 su = g[(size_t)i*64 + t];
    float v0 = (a0 + sw*bflo(su))*rD + bc.x;
    float v1 = (a1 + sw*bfhi(su))*rD + bc.y;
    h2out[(size_t)i*192 + t] = f2bf(elu_f(v0)) | (f2bf(elu_f(v1)) << 16);
  }
}

// ---------------- SAGE mean (no self loops), inside Acat ----------------

__global__ __launch_bounds__(256) void sage_mean(const uint32* __restrict__ h2,  // pre-offset +64, stride 192
    const int* __restrict__ rowptr, const int* __restrict__ col,
    uint32* __restrict__ mout, int N)                                             // stride 192
{
  int t = threadIdx.x & 63;
  int w = __builtin_amdgcn_readfirstlane(threadIdx.x >> 6);
  int stride = gridDim.x*4;
  for(int i = blockIdx.x*4 + w; i < N; i += stride){
    int beg = rowptr[i], end = rowptr[i+1];
    float a0 = 0.f, a1 = 0.f;
#define SAGE_ROW(q) { int row = __builtin_amdgcn_readlane(s, q); \
    uint32 u = h2[(size_t)row*192 + t]; a0 += bflo(u); a1 += bfhi(u); }
    for(int c0 = beg; c0 < end; c0 += 64){
      int p = c0 + t;
      int cl = end - c0; if(cl > 64) cl = 64;
      int s = (p < end) ? col[p] : 0;
      int q = 0;
      for(; q + 4 <= cl; q += 4){ SAGE_ROW(q) SAGE_ROW(q+1) SAGE_ROW(q+2) SAGE_ROW(q+3) }
      for(; q < cl; q++){ SAGE_ROW(q) }
    }
#undef SAGE_ROW
    float inv = 1.f/fmaxf((float)(end - beg), 1.f);
    mout[(size_t)i*192 + t] = f2bf(a0*inv) | (f2bf(a1*inv) << 16);
  }
}

// ---------------- classifier: out = elu(h3@w1+b1)@w2 + b2  (h3 bf16) ----------------

__global__ __launch_bounds__(256) void classifier_kernel(const uint32* __restrict__ h3,  // stride 32 uints
    const float* __restrict__ w1, const float* __restrict__ b1,
    const float* __restrict__ w2, const float* __restrict__ b2,
    float* __restrict__ out, int N)
{
  __shared__ float hs[8][64];
  __shared__ float zs[8][32];
  int node0 = blockIdx.x*8;
  int t = threadIdx.x;
  {
    int r = t >> 5, cp = t & 31;
    int nd = node0 + r;
    uint32 u = (nd < N) ? h3[(size_t)nd*32 + cp] : 0u;
    hs[r][2*cp]   = bflo(u);
    hs[r][2*cp+1] = bfhi(u);
  }
  __syncthreads();
  int nn = t >> 5, ln = t & 31;
  float acc = b1[ln];
#pragma unroll
  for(int k = 0; k < 64; k++) acc += hs[nn][k]*w1[k*32 + ln];
  zs[nn][ln] = elu_f(acc);
  __syncthreads();
  int node = node0 + nn;
  if(ln < 2 && node < N){
    float o = b2[ln];
#pragma unroll
    for(int k = 0; k < 32; k++) o += zs[nn][k]*w2[k*2 + ln];
    out[(size_t)node*2 + ln] = o;
  }
}

// ---------------- launch ----------------

extern "C" void kernel_launch(void* const* d_in, const int* in_sizes, int n_in,
                              void* d_out, int out_size, void* d_ws, size_t ws_size,
                              hipStream_t stream)
{
  (void)n_in; (void)out_size; (void)ws_size;
  const float* x      = (const float*)d_in[0];
  const int*   ei     = (const int*)  d_in[1];
  const float* w_in   = (const float*)d_in[2];
  const float* b_in   = (const float*)d_in[3];
  const float* w_gcn  = (const float*)d_in[4];
  const float* b_gcn  = (const float*)d_in[5];
  const float* bn1_g  = (const float*)d_in[6];
  const float* bn1_b  = (const float*)d_in[7];
  const float* bn1_m  = (const float*)d_in[8];
  const float* bn1_v  = (const float*)d_in[9];
  const float* w_gat  = (const float*)d_in[10];
  const float* att_s  = (const float*)d_in[11];
  const float* att_d  = (const float*)d_in[12];
  const float* b_gat  = (const float*)d_in[13];
  const float* bn2_g  = (const float*)d_in[14];
  const float* bn2_b  = (const float*)d_in[15];
  const float* bn2_m  = (const float*)d_in[16];
  const float* bn2_v  = (const float*)d_in[17];
  const float* w_sl   = (const float*)d_in[18];
  const float* b_sage = (const float*)d_in[19];
  const float* w_sr   = (const float*)d_in[20];
  const float* bn3_g  = (const float*)d_in[21];
  const float* bn3_b  = (const float*)d_in[22];
  const float* bn3_m  = (const float*)d_in[23];
  const float* bn3_v  = (const float*)d_in[24];
  const float* w_res  = (const float*)d_in[25];
  const float* b_res  = (const float*)d_in[26];
  const float* w_c1   = (const float*)d_in[27];
  const float* b_c1   = (const float*)d_in[28];
  const float* w_c2   = (const float*)d_in[29];
  const float* b_c2   = (const float*)d_in[30];

  const int F_IN = 165;
  int N = in_sizes[0]/F_IN;
  int E = in_sizes[1]/2;
  const int* srcp = ei;
  const int* dstp = ei + E;
  int nb = (N + 1023) >> 10;

  char* p = (char*)d_ws;
  auto alloc = [&](size_t bytes) -> char* {
    char* q = p; p += (bytes + 255) & ~(size_t)255; return q;
  };
  ushort16* Acat  = (ushort16*)alloc((size_t)N*384*2);   // [mean_nb | h2 | h]
  ushort16* xb    = (ushort16*)alloc((size_t)N*192*2);   // later reused for h1
  ushort16* bufG  = (ushort16*)alloc((size_t)N*128*2);   // hw2 -> g -> h3(bf16)
  float* a_src    = (float*)alloc((size_t)N*2*4);
  float* a_dst    = (float*)alloc((size_t)N*2*4);
  float* ess      = (float*)alloc((size_t)N*2*4);
  float* dinv     = (float*)alloc((size_t)N*4);
  int* cnt        = (int*)alloc((size_t)N*4);
  int* fill       = (int*)alloc((size_t)N*4);
  int* rowptr     = (int*)alloc((size_t)(N+1)*4);
  int* part       = (int*)alloc((size_t)N*4);
  int* bsum       = (int*)alloc(1024*4);
  int* boff       = (int*)alloc(1024*4);
  int* col        = (int*)alloc((size_t)E*4);
  float* s1       = (float*)alloc(128*4);
  float* b1c      = (float*)alloc(128*4);
  float* s2       = (float*)alloc(128*4);
  float* b2c      = (float*)alloc(128*4);
  float* atts2    = (float*)alloc(128*4);
  float* attd2    = (float*)alloc(128*4);
  float* s3       = (float*)alloc(64*4);
  float* bias3    = (float*)alloc(64*4);
  ushort16* pw_in  = (ushort16*)alloc(6*4*128*16);   // 48 KB
  ushort16* pw_gcn = (ushort16*)alloc(4*4*128*16);   // 32 KB
  ushort16* pw_gat = (ushort16*)alloc(4*4*128*16);
  ushort16* pw_cat = (ushort16*)alloc(12*4*64*16);   // 48 KB

  ushort16* h1 = xb;                 // xb dead after GEMM1
  ushort16* h3 = bufG;               // g dead after gat_gather

  // cnt and fill are adjacent allocations: one memset covers both (incl. pad)
  hipMemsetAsync(cnt, 0, (size_t)((char*)(fill + N) - (char*)cnt), stream);

  count_deg_kernel<<<(E+255)/256, 256, 0, stream>>>(dstp, E, cnt);
  scan_blocks<<<nb, 1024, 0, stream>>>(cnt, N, part, bsum);
  scan_bsum<<<1, 1024, 0, stream>>>(bsum, nb, boff, rowptr, N);
  scan_add_dinv<<<(N+255)/256, 256, 0, stream>>>(part, boff, cnt, N, rowptr, dinv);
  scatter_kernel<<<(E+255)/256, 256, 0, stream>>>(srcp, dstp, E, rowptr, fill, col);

  cvt_x<<<(N*48 + 255)/256, 256, 0, stream>>>(x, (uint2*)xb, N*48);
  prep_scales<<<1, 128, 0, stream>>>(bn1_g, bn1_b, bn1_m, bn1_v, b_gcn,
                                     bn2_g, bn2_b, bn2_m, bn2_v, b_gat,
                                     att_s, att_d,
                                     bn3_g, bn3_b, bn3_m, bn3_v, b_sage, b_res,
                                     s1, b1c, s2, b2c, atts2, attd2, s3, bias3);
  pack_all<<<320, 256, 0, stream>>>(w_in, w_gcn, w_gat, w_sl, w_sr, w_res,
                                    s1, s2, s3, pw_in, pw_gcn, pw_gat, pw_cat);

  int g128 = (N + 127)/128;
  int g256 = (N + 255)/256;
  int gagg = (N + 3)/4; if(gagg > 4096) gagg = 4096;

  // h = elu(x@w_in + b_in)  -> Acat[:,256:384]
  mfma_gemm<6,128,1><<<g128, 256, 0, stream>>>(xb, 192, (const uint4v*)pw_in, b_in,
      (void*)(Acat + 256), 384, N, nullptr, nullptr, nullptr, nullptr, nullptr, nullptr);
  // hw2 = (h@(w_gcn*s1))*dinv[row] -> bufG
  mfma_gemm<4,128,4><<<g128, 256, 0, stream>>>(Acat + 256, 384, (const uint4v*)pw_gcn, nullptr,
      (void*)bufG, 128, N, dinv, nullptr, nullptr, nullptr, nullptr, nullptr);
  // h1 = elu(sum(hw2)*di + b1c)
  gcn_agg<<<gagg, 256, 0, stream>>>((const uint32*)bufG, rowptr, col, dinv, b1c,
                                    (uint32*)h1, N);
  // g' = h1@(w_gat*s2) -> bufG, + fused attention scalars / self logits
  mfma_gemm<4,128,3><<<g128, 256, 0, stream>>>(h1, 128, (const uint4v*)pw_gat, nullptr,
      (void*)bufG, 128, N, nullptr, atts2, attd2, a_src, a_dst, ess);
  // h2 -> Acat[:,128:256]   (softmax fully in-register per dst row)
  gat_gather<<<gagg, 256, 0, stream>>>((const uint32*)bufG, rowptr, col, a_src, a_dst, ess,
                                       b2c, (uint32*)Acat + 64, N);
  // mean_nb -> Acat[:,0:128]
  sage_mean<<<gagg, 256, 0, stream>>>((const uint32*)Acat + 64, rowptr, col, (uint32*)Acat, N);
  // h3 = elu((Acat @ [w_sl*s3; w_sr*s3; w_res]) + bias3) -> bf16
  mfma_gemm<12,64,1><<<g256, 256, 0, stream>>>(Acat, 384, (const uint4v*)pw_cat, bias3,
      (void*)h3, 64, N, nullptr, nullptr, nullptr, nullptr, nullptr, nullptr);
  classifier_kernel<<<(N+7)/8, 256, 0, stream>>>((const uint32*)h3, w_c1, b_c1, w_c2, b_c2,
                                                 (float*)d_out, N);
}

// Round 9
// 332.673 us; speedup vs baseline: 1.5594x; 1.0124x over previous
//
#include <hip/hip_runtime.h>
#include <cstdint>
#include <cstddef>

#define BN_EPS 1e-5f

typedef __attribute__((ext_vector_type(8))) short short8v;
typedef __attribute__((ext_vector_type(4))) float float4v;
typedef __attribute__((ext_vector_type(4))) unsigned int uint4v;
typedef unsigned int uint32;
typedef unsigned short ushort16;

__device__ __forceinline__ float elu_f(float v){ return v > 0.f ? v : expm1f(v); }
__device__ __forceinline__ float leaky_f(float v){ return v > 0.f ? v : 0.2f*v; }
__device__ __forceinline__ uint32 f2bf(float f){
  uint32 b = __float_as_uint(f);
  return (b + 0x7fffu + ((b >> 16) & 1u)) >> 16;        // RNE
}
__device__ __forceinline__ float bflo(uint32 u){ return __uint_as_float(u << 16); }
__device__ __forceinline__ float bfhi(uint32 u){ return __uint_as_float(u & 0xffff0000u); }
__device__ __forceinline__ float readlane_f(float v, int l){
  return __int_as_float(__builtin_amdgcn_readlane(__float_as_int(v), l));
}

// ---------------- graph preprocessing: CSR by dst ----------------

__global__ void count_deg_kernel(const int* __restrict__ dst, int E, int* __restrict__ cnt){
  int i = blockIdx.x*blockDim.x + threadIdx.x;
  if(i < E) atomicAdd(&cnt[dst[i]], 1);
}

__global__ __launch_bounds__(1024) void scan_blocks(const int* __restrict__ cnt, int n,
                                                    int* __restrict__ part, int* __restrict__ bsum){
  __shared__ int wsum[16];
  int tid = threadIdx.x, lane = tid & 63, w = tid >> 6;
  int i = blockIdx.x*1024 + tid;
  int v = (i < n) ? cnt[i] : 0;
  int sv = v;
#pragma unroll
  for(int o = 1; o < 64; o <<= 1){
    int u = __shfl_up(sv, o);
    if(lane >= o) sv += u;
  }
  if(lane == 63) wsum[w] = sv;
  __syncthreads();
  int woff = 0;
#pragma unroll
  for(int q = 0; q < 16; q++) woff += (q < w) ? wsum[q] : 0;
  if(i < n) part[i] = woff + sv - v;
  if(tid == 1023) bsum[blockIdx.x] = woff + sv;
}

__global__ __launch_bounds__(1024) void scan_bsum(const int* __restrict__ bsum, int nb,
                                                  int* __restrict__ boff, int* __restrict__ rowptr, int n){
  __shared__ int wsum[16];
  int tid = threadIdx.x, lane = tid & 63, w = tid >> 6;
  int v = (tid < nb) ? bsum[tid] : 0;
  int sv = v;
#pragma unroll
  for(int o = 1; o < 64; o <<= 1){
    int u = __shfl_up(sv, o);
    if(lane >= o) sv += u;
  }
  if(lane == 63) wsum[w] = sv;
  __syncthreads();
  int woff = 0;
#pragma unroll
  for(int q = 0; q < 16; q++) woff += (q < w) ? wsum[q] : 0;
  if(tid < nb) boff[tid] = woff + sv - v;
  if(tid == 1023) rowptr[n] = woff + sv;
}

__global__ void scan_add_dinv(const int* __restrict__ part, const int* __restrict__ boff,
                              const int* __restrict__ cnt, int n,
                              int* __restrict__ rowptr, float* __restrict__ dinv){
  int i = blockIdx.x*blockDim.x + threadIdx.x;
  if(i < n){
    rowptr[i] = part[i] + boff[i >> 10];
    dinv[i] = rsqrtf((float)cnt[i] + 1.0f);   // deg includes self loop
  }
}

__global__ void scatter_kernel(const int* __restrict__ src, const int* __restrict__ dst, int E,
                               const int* __restrict__ rowptr, int* __restrict__ fill,
                               int* __restrict__ col){
  int i = blockIdx.x*blockDim.x + threadIdx.x;
  if(i < E){
    int s = src[i], d = dst[i];
    int p = rowptr[d] + atomicAdd(&fill[d], 1);
    col[p] = s;
  }
}

// ---------------- x -> bf16, K padded 165 -> 192, uint2 writes ----------------

__global__ __launch_bounds__(256) void cvt_x(const float* __restrict__ x, uint2* __restrict__ xb, int total){
  int idx = blockIdx.x*256 + threadIdx.x;     // over N*48 uint2
  if(idx >= total) return;
  int row = idx/48;
  int cp = idx - row*48;
  int c = cp*4;
  const float* xr = x + (size_t)row*165;
  float v0 = (c   < 165) ? xr[c]   : 0.f;
  float v1 = (c+1 < 165) ? xr[c+1] : 0.f;
  float v2 = (c+2 < 165) ? xr[c+2] : 0.f;
  float v3 = (c+3 < 165) ? xr[c+3] : 0.f;
  xb[idx] = make_uint2(f2bf(v0) | (f2bf(v1) << 16), f2bf(v2) | (f2bf(v3) << 16));
}

// ---------------- BN folding: per-channel scales + combined biases ----------------

__global__ void prep_scales(const float* __restrict__ bn1_g, const float* __restrict__ bn1_b,
    const float* __restrict__ bn1_m, const float* __restrict__ bn1_v, const float* __restrict__ b_gcn,
    const float* __restrict__ bn2_g, const float* __restrict__ bn2_b,
    const float* __restrict__ bn2_m, const float* __restrict__ bn2_v, const float* __restrict__ b_gat,
    const float* __restrict__ att_s, const float* __restrict__ att_d,
    const float* __restrict__ bn3_g, const float* __restrict__ bn3_b,
    const float* __restrict__ bn3_m, const float* __restrict__ bn3_v,
    const float* __restrict__ b_sage, const float* __restrict__ b_res,
    float* __restrict__ s1, float* __restrict__ b1c,
    float* __restrict__ s2, float* __restrict__ b2c,
    float* __restrict__ atts2, float* __restrict__ attd2,
    float* __restrict__ s3, float* __restrict__ bias3){
  int c = threadIdx.x;   // 128
  float v1 = bn1_g[c]*rsqrtf(bn1_v[c] + BN_EPS);
  s1[c] = v1;
  b1c[c] = (b_gcn[c] - bn1_m[c])*v1 + bn1_b[c];
  float v2 = bn2_g[c]*rsqrtf(bn2_v[c] + BN_EPS);
  s2[c] = v2;
  b2c[c] = (b_gat[c] - bn2_m[c])*v2 + bn2_b[c];
  atts2[c] = att_s[c]/v2;
  attd2[c] = att_d[c]/v2;
  if(c < 64){
    float v3 = bn3_g[c]*rsqrtf(bn3_v[c] + BN_EPS);
    s3[c] = v3;
    bias3[c] = (b_sage[c] - bn3_m[c])*v3 + bn3_b[c] + b_res[c];
  }
}

// ---------------- weight packing (one launch): packed[kgrp][col][8] bf16 ----------------

__device__ __forceinline__ void pack_region(const float* __restrict__ W, int K, int NOUT, int kbase, int idx,
                                            const float* __restrict__ scale, ushort16* __restrict__ out){
  int k = idx / NOUT, c = idx - k*NOUT;
  float v = (k < K) ? W[(size_t)k*NOUT + c] : 0.f;
  if(scale) v *= scale[c];
  int pk = kbase + k;
  out[(size_t)(pk >> 3)*NOUT*8 + (size_t)c*8 + (pk & 7)] = (ushort16)f2bf(v);
}

__global__ __launch_bounds__(256) void pack_all(const float* __restrict__ w_in, const float* __restrict__ w_gcn,
    const float* __restrict__ w_gat, const float* __restrict__ w_sl, const float* __restrict__ w_sr,
    const float* __restrict__ w_res,
    const float* __restrict__ s1, const float* __restrict__ s2, const float* __restrict__ s3,
    ushort16* __restrict__ pw_in, ushort16* __restrict__ pw_gcn,
    ushort16* __restrict__ pw_gat, ushort16* __restrict__ pw_cat){
  int b = blockIdx.x, t = threadIdx.x;
  if(b < 96)       pack_region(w_in,  165, 128, 0,   b*256 + t,        nullptr, pw_in);
  else if(b < 160) pack_region(w_gcn, 128, 128, 0,   (b-96)*256 + t,   s1,      pw_gcn);
  else if(b < 224) pack_region(w_gat, 128, 128, 0,   (b-160)*256 + t,  s2,      pw_gat);
  else if(b < 256) pack_region(w_sl,  128, 64,  0,   (b-224)*256 + t,  s3,      pw_cat);
  else if(b < 288) pack_region(w_sr,  128, 64,  128, (b-256)*256 + t,  s3,      pw_cat);
  else             pack_region(w_res, 128, 64,  256, (b-288)*256 + t,  nullptr, pw_cat);
}

// ---------------- MFMA bf16 GEMM ----------------
// EPI: 0 raw->bf16, 1 bias+elu->bf16, 3 raw->bf16 + fused GAT attention epilogue,
//      4 row-scale by dinv[r] -> bf16 (GCN fold)

template<int KSTEPS, int NOUT, int EPI>
__global__ __launch_bounds__(256) void mfma_gemm(
    const ushort16* __restrict__ A, int lda,
    const uint4v* __restrict__ pw,
    const float* __restrict__ bias,
    void* __restrict__ out, int ldo, int N,
    const float* __restrict__ dinv,
    const float* __restrict__ atts2, const float* __restrict__ attd2,
    float* __restrict__ a_src, float* __restrict__ a_dst,
    float* __restrict__ ess)
{
  constexpr int LDSV = KSTEPS*4*NOUT;
  __shared__ uint4v wlds[LDSV];
  int t = threadIdx.x;
#pragma unroll
  for(int q = 0; q < LDSV/256; q++)
    wlds[q*256 + t] = pw[q*256 + t];
  __syncthreads();

  int wid = t >> 6, lane = t & 63;
  int wm, wn;
  if(NOUT == 128){ wm = wid >> 1; wn = wid & 1; } else { wm = wid; wn = 0; }
  constexpr int MTILE = (NOUT == 128) ? 128 : 256;
  long row0 = (long)blockIdx.x*MTILE + wm*64;
  int l15 = lane & 15, lk = lane >> 4;
  int wn64 = wn*64;
  const ushort16* wl = (const ushort16*)wlds;

  float4v acc[4][4];
#pragma unroll
  for(int fm = 0; fm < 4; fm++)
#pragma unroll
    for(int fn = 0; fn < 4; fn++) acc[fm][fn] = (float4v){0.f,0.f,0.f,0.f};

  const ushort16* abase[4];
#pragma unroll
  for(int fm = 0; fm < 4; fm++){
    long r = row0 + fm*16 + l15;
    if(r > (long)N - 1) r = (long)N - 1;
    abase[fm] = A + r*(size_t)lda + lk*8;
  }

  short8v a[4];
#pragma unroll
  for(int fm = 0; fm < 4; fm++) a[fm] = *(const short8v*)(abase[fm]);

#pragma unroll
  for(int ks = 0; ks < KSTEPS; ks++){
    short8v b[4];
#pragma unroll
    for(int fn = 0; fn < 4; fn++){
      int c = wn64 + fn*16 + l15;
      b[fn] = *(const short8v*)(wl + ((size_t)((ks*4 + lk)*NOUT + c))*8);
    }
    short8v an[4];
    if(ks + 1 < KSTEPS){
#pragma unroll
      for(int fm = 0; fm < 4; fm++) an[fm] = *(const short8v*)(abase[fm] + (ks + 1)*32);
    }
#pragma unroll
    for(int fm = 0; fm < 4; fm++)
#pragma unroll
      for(int fn = 0; fn < 4; fn++)
        acc[fm][fn] = __builtin_amdgcn_mfma_f32_16x16x32_bf16(a[fm], b[fn], acc[fm][fn], 0, 0, 0);
    if(ks + 1 < KSTEPS){
#pragma unroll
      for(int fm = 0; fm < 4; fm++) a[fm] = an[fm];
    }
  }

  // C/D layout: col = lane&15, row = (lane>>4)*4 + reg
#pragma unroll
  for(int fm = 0; fm < 4; fm++){
#pragma unroll
    for(int rr = 0; rr < 4; rr++){
      long r = row0 + fm*16 + lk*4 + rr;
      if(r < N){
        float dr = 0.f;
        if constexpr(EPI == 4) dr = dinv[r];
#pragma unroll
        for(int fn = 0; fn < 4; fn++){
          int c = wn64 + fn*16 + l15;
          float v = acc[fm][fn][rr];
          if constexpr(EPI == 1){ v += bias[c]; v = elu_f(v); }
          if constexpr(EPI == 4){ v *= dr; }
          ((ushort16*)out)[r*(size_t)ldo + c] = (ushort16)f2bf(v);
        }
      }
    }
  }

  if constexpr(EPI == 3){
    // fused GAT attention scalars: wn selects head (cols 0-63 = head0, 64-127 = head1)
    float as2[4], ad2[4];
#pragma unroll
    for(int fn = 0; fn < 4; fn++){
      int c = wn64 + fn*16 + l15;
      as2[fn] = atts2[c]; ad2[fn] = attd2[c];
    }
#pragma unroll
    for(int fm = 0; fm < 4; fm++){
#pragma unroll
      for(int rr = 0; rr < 4; rr++){
        float p1 = 0.f, p2 = 0.f;
#pragma unroll
        for(int fn = 0; fn < 4; fn++){
          p1 += acc[fm][fn][rr]*as2[fn];
          p2 += acc[fm][fn][rr]*ad2[fn];
        }
#pragma unroll
        for(int o = 1; o < 16; o <<= 1){
          p1 += __shfl_xor(p1, o);
          p2 += __shfl_xor(p2, o);
        }
        long r = row0 + fm*16 + lk*4 + rr;
        if(l15 == 0 && r < N){
          a_src[2*r + wn] = p1;
          a_dst[2*r + wn] = p2;
          ess[2*r + wn] = __expf(leaky_f(p1 + p2));   // self-exp, M=0 (exact: M cancels)
        }
      }
    }
  }
}

// ---------------- GCN aggregation (dinv pre-folded) + BN1 + ELU ----------------
// node-pair per wave: 2 interleaved gather streams double in-flight loads

__global__ __launch_bounds__(256) void gcn_agg(const uint32* __restrict__ hw2,   // stride 64 uints
    const int* __restrict__ rowptr, const int* __restrict__ col,
    const float* __restrict__ dinv, const float* __restrict__ b1c,
    uint32* __restrict__ h1, int N)
{
  int t = threadIdx.x & 63;
  int w = __builtin_amdgcn_readfirstlane(threadIdx.x >> 6);
  float2 bc = ((const float2*)b1c)[t];
  int stride = gridDim.x*8;
  for(int i0 = (blockIdx.x*4 + w)*2; i0 < N; i0 += stride){
    int i1 = i0 + 1;
    bool has1 = i1 < N;
    int beg0 = rowptr[i0];
    int end0 = rowptr[i0+1];
    int beg1 = end0;                       // rowptr[i1] == end0 (consecutive nodes)
    int end1 = has1 ? rowptr[i1+1] : end0;
    float di0 = dinv[i0];
    float di1 = has1 ? dinv[i1] : 0.f;
    uint32 su0 = hw2[(size_t)i0*64 + t];
    float a00 = bflo(su0), a01 = bfhi(su0);   // self loop (dinv folded into hw2)
    float a10 = 0.f, a11 = 0.f;
    if(has1){ uint32 su1 = hw2[(size_t)i1*64 + t]; a10 = bflo(su1); a11 = bfhi(su1); }
#define R0(q) { int row = __builtin_amdgcn_readlane(s0, q); \
    uint32 u = hw2[(size_t)row*64 + t]; a00 += bflo(u); a01 += bfhi(u); }
#define R1(q) { int row = __builtin_amdgcn_readlane(s1, q); \
    uint32 u = hw2[(size_t)row*64 + t]; a10 += bflo(u); a11 += bfhi(u); }
    for(int c0 = beg0, c1 = beg1; c0 < end0 || c1 < end1; c0 += 64, c1 += 64){
      int p0 = c0 + t, p1 = c1 + t;
      int s0 = (p0 < end0) ? col[p0] : 0;
      int s1 = (p1 < end1) ? col[p1] : 0;
      int cl0 = end0 - c0; cl0 = cl0 < 0 ? 0 : (cl0 > 64 ? 64 : cl0);
      int cl1 = end1 - c1; cl1 = cl1 < 0 ? 0 : (cl1 > 64 ? 64 : cl1);
      int m = cl0 < cl1 ? cl0 : cl1;
      int q = 0;
      for(; q + 2 <= m; q += 2){ R0(q) R1(q) R0(q+1) R1(q+1) }
      for(; q < m; q++){ R0(q) R1(q) }
      for(int qa = m; qa < cl0; qa++){ R0(qa) }
      for(int qb = m; qb < cl1; qb++){ R1(qb) }
    }
#undef R0
#undef R1
    h1[(size_t)i0*64 + t] = f2bf(elu_f(a00*di0 + bc.x)) | (f2bf(elu_f(a01*di0 + bc.y)) << 16);
    if(has1)
      h1[(size_t)i1*64 + t] = f2bf(elu_f(a10*di1 + bc.x)) | (f2bf(elu_f(a11*di1 + bc.y)) << 16);
  }
}

// ---------------- GAT gather: no-max softmax (exact) + weighted sum + BN2 + ELU ----------
// writes h2 (bf16) into Acat[:,128:256]  (out pre-offset, stride 192 uints)

__global__ __launch_bounds__(256) void gat_gather(const uint32* __restrict__ g,   // stride 64
    const int* __restrict__ rowptr, const int* __restrict__ col,
    const float* __restrict__ a_src, const float* __restrict__ a_dst,
    const float* __restrict__ ess, const float* __restrict__ b2c,
    uint32* __restrict__ h2out, int N)
{
  int t = threadIdx.x & 63;
  int w = __builtin_amdgcn_readfirstlane(threadIdx.x >> 6);
  float2 bc = ((const float2*)b2c)[t];
  int hl = t >> 5;
  int stride = gridDim.x*4;
  for(int i = blockIdx.x*4 + w; i < N; i += stride){
    int beg = rowptr[i], end = rowptr[i+1];
    int deg = end - beg;
    float2 ad = ((const float2*)a_dst)[i];
    float sw0 = ess[2*i], sw1 = ess[2*i+1];    // exp(self logit), M=0
    float d0 = 0.f, d1 = 0.f, a0 = 0.f, a1 = 0.f;
#define GAT_ROWF(q) { int row = __builtin_amdgcn_readlane(s, q); \
    float w0q = readlane_f(e0, q); \
    float w1q = readlane_f(e1, q); \
    float wq = hl ? w1q : w0q; \
    uint32 u = g[(size_t)row*64 + t]; a0 += wq*bflo(u); a1 += wq*bfhi(u); }
    if(deg <= 64){
      int p = beg + t;
      int s = 0; float e0 = 0.f, e1 = 0.f;
      if(p < end){
        s = col[p];
        float2 as = ((const float2*)a_src)[s];
        e0 = __expf(leaky_f(as.x + ad.x));
        e1 = __expf(leaky_f(as.y + ad.y));
      }
      d0 = e0; d1 = e1;
      int q = 0;
      for(; q + 4 <= deg; q += 4){ GAT_ROWF(q) GAT_ROWF(q+1) GAT_ROWF(q+2) GAT_ROWF(q+3) }
      for(; q < deg; q++){ GAT_ROWF(q) }
    } else {
      for(int c0 = beg; c0 < end; c0 += 64){
        int p = c0 + t;
        int cl = end - c0; if(cl > 64) cl = 64;
        float e0 = 0.f, e1 = 0.f; int s = 0;
        if(p < end){
          s = col[p];
          float2 as = ((const float2*)a_src)[s];
          e0 = __expf(leaky_f(as.x + ad.x));
          e1 = __expf(leaky_f(as.y + ad.y));
        }
        d0 += e0; d1 += e1;
        int q = 0;
        for(; q + 4 <= cl; q += 4){ GAT_ROWF(q) GAT_ROWF(q+1) GAT_ROWF(q+2) GAT_ROWF(q+3) }
        for(; q < cl; q++){ GAT_ROWF(q) }
      }
    }
#undef GAT_ROWF
#pragma unroll
    for(int o = 32; o > 0; o >>= 1){ d0 += __shfl_xor(d0, o); d1 += __shfl_xor(d1, o); }
    float rD = 1.f/(((hl ? d1 : d0) + (hl ? sw1 : sw0)) + 1e-16f);
    float sw = hl ? sw1 : sw0;
    uint32 su = g[(size_t)i*64 + t];
    float v0 = (a0 + sw*bflo(su))*rD + bc.x;
    float v1 = (a1 + sw*bfhi(su))*rD + bc.y;
    h2out[(size_t)i*192 + t] = f2bf(elu_f(v0)) | (f2bf(elu_f(v1)) << 16);
  }
}

// ---------------- SAGE mean (no self loops), node-pair per wave, inside Acat ----------------

__global__ __launch_bounds__(256) void sage_mean(const uint32* __restrict__ h2,  // pre-offset +64, stride 192
    const int* __restrict__ rowptr, const int* __restrict__ col,
    uint32* __restrict__ mout, int N)                                             // stride 192
{
  int t = threadIdx.x & 63;
  int w = __builtin_amdgcn_readfirstlane(threadIdx.x >> 6);
  int stride = gridDim.x*8;
  for(int i0 = (blockIdx.x*4 + w)*2; i0 < N; i0 += stride){
    int i1 = i0 + 1;
    bool has1 = i1 < N;
    int beg0 = rowptr[i0];
    int end0 = rowptr[i0+1];
    int beg1 = end0;
    int end1 = has1 ? rowptr[i1+1] : end0;
    float a00 = 0.f, a01 = 0.f, a10 = 0.f, a11 = 0.f;
#define S0(q) { int row = __builtin_amdgcn_readlane(s0, q); \
    uint32 u = h2[(size_t)row*192 + t]; a00 += bflo(u); a01 += bfhi(u); }
#define S1(q) { int row = __builtin_amdgcn_readlane(s1, q); \
    uint32 u = h2[(size_t)row*192 + t]; a10 += bflo(u); a11 += bfhi(u); }
    for(int c0 = beg0, c1 = beg1; c0 < end0 || c1 < end1; c0 += 64, c1 += 64){
      int p0 = c0 + t, p1 = c1 + t;
      int s0 = (p0 < end0) ? col[p0] : 0;
      int s1 = (p1 < end1) ? col[p1] : 0;
      int cl0 = end0 - c0; cl0 = cl0 < 0 ? 0 : (cl0 > 64 ? 64 : cl0);
      int cl1 = end1 - c1; cl1 = cl1 < 0 ? 0 : (cl1 > 64 ? 64 : cl1);
      int m = cl0 < cl1 ? cl0 : cl1;
      int q = 0;
      for(; q + 2 <= m; q += 2){ S0(q) S1(q) S0(q+1) S1(q+1) }
      for(; q < m; q++){ S0(q) S1(q) }
      for(int qa = m; qa < cl0; qa++){ S0(qa) }
      for(int qb = m; qb < cl1; qb++){ S1(qb) }
    }
#undef S0
#undef S1
    float inv0 = 1.f/fmaxf((float)(end0 - beg0), 1.f);
    mout[(size_t)i0*192 + t] = f2bf(a00*inv0) | (f2bf(a01*inv0) << 16);
    if(has1){
      float inv1 = 1.f/fmaxf((float)(end1 - beg1), 1.f);
      mout[(size_t)i1*192 + t] = f2bf(a10*inv1) | (f2bf(a11*inv1) << 16);
    }
  }
}

// ---------------- classifier: out = elu(h3@w1+b1)@w2 + b2  (h3 bf16) ----------------

__global__ __launch_bounds__(256) void classifier_kernel(const uint32* __restrict__ h3,  // stride 32 uints
    const float* __restrict__ w1, const float* __restrict__ b1,
    const float* __restrict__ w2, const float* __restrict__ b2,
    float* __restrict__ out, int N)
{
  __shared__ float hs[8][64];
  __shared__ float zs[8][32];
  int node0 = blockIdx.x*8;
  int t = threadIdx.x;
  {
    int r = t >> 5, cp = t & 31;
    int nd = node0 + r;
    uint32 u = (nd < N) ? h3[(size_t)nd*32 + cp] : 0u;
    hs[r][2*cp]   = bflo(u);
    hs[r][2*cp+1] = bfhi(u);
  }
  __syncthreads();
  int nn = t >> 5, ln = t & 31;
  float acc = b1[ln];
#pragma unroll
  for(int k = 0; k < 64; k++) acc += hs[nn][k]*w1[k*32 + ln];
  zs[nn][ln] = elu_f(acc);
  __syncthreads();
  int node = node0 + nn;
  if(ln < 2 && node < N){
    float o = b2[ln];
#pragma unroll
    for(int k = 0; k < 32; k++) o += zs[nn][k]*w2[k*2 + ln];
    out[(size_t)node*2 + ln] = o;
  }
}

// ---------------- launch ----------------

extern "C" void kernel_launch(void* const* d_in, const int* in_sizes, int n_in,
                              void* d_out, int out_size, void* d_ws, size_t ws_size,
                              hipStream_t stream)
{
  (void)n_in; (void)out_size; (void)ws_size;
  const float* x      = (const float*)d_in[0];
  const int*   ei     = (const int*)  d_in[1];
  const float* w_in   = (const float*)d_in[2];
  const float* b_in   = (const float*)d_in[3];
  const float* w_gcn  = (const float*)d_in[4];
  const float* b_gcn  = (const float*)d_in[5];
  const float* bn1_g  = (const float*)d_in[6];
  const float* bn1_b  = (const float*)d_in[7];
  const float* bn1_m  = (const float*)d_in[8];
  const float* bn1_v  = (const float*)d_in[9];
  const float* w_gat  = (const float*)d_in[10];
  const float* att_s  = (const float*)d_in[11];
  const float* att_d  = (const float*)d_in[12];
  const float* b_gat  = (const float*)d_in[13];
  const float* bn2_g  = (const float*)d_in[14];
  const float* bn2_b  = (const float*)d_in[15];
  const float* bn2_m  = (const float*)d_in[16];
  const float* bn2_v  = (const float*)d_in[17];
  const float* w_sl   = (const float*)d_in[18];
  const float* b_sage = (const float*)d_in[19];
  const float* w_sr   = (const float*)d_in[20];
  const float* bn3_g  = (const float*)d_in[21];
  const float* bn3_b  = (const float*)d_in[22];
  const float* bn3_m  = (const float*)d_in[23];
  const float* bn3_v  = (const float*)d_in[24];
  const float* w_res  = (const float*)d_in[25];
  const float* b_res  = (const float*)d_in[26];
  const float* w_c1   = (const float*)d_in[27];
  const float* b_c1   = (const float*)d_in[28];
  const float* w_c2   = (const float*)d_in[29];
  const float* b_c2   = (const float*)d_in[30];

  const int F_IN = 165;
  int N = in_sizes[0]/F_IN;
  int E = in_sizes[1]/2;
  const int* srcp = ei;
  const int* dstp = ei + E;
  int nb = (N + 1023) >> 10;

  char* p = (char*)d_ws;
  auto alloc = [&](size_t bytes) -> char* {
    char* q = p; p += (bytes + 255) & ~(size_t)255; return q;
  };
  ushort16* Acat  = (ushort16*)alloc((size_t)N*384*2);   // [mean_nb | h2 | h]
  ushort16* xb    = (ushort16*)alloc((size_t)N*192*2);   // later reused for h1
  ushort16* bufG  = (ushort16*)alloc((size_t)N*128*2);   // hw2 -> g -> h3(bf16)
  float* a_src    = (float*)alloc((size_t)N*2*4);
  float* a_dst    = (float*)alloc((size_t)N*2*4);
  float* ess      = (float*)alloc((size_t)N*2*4);
  float* dinv     = (float*)alloc((size_t)N*4);
  int* cnt        = (int*)alloc((size_t)N*4);
  int* fill       = (int*)alloc((size_t)N*4);
  int* rowptr     = (int*)alloc((size_t)(N+1)*4);
  int* part       = (int*)alloc((size_t)N*4);
  int* bsum       = (int*)alloc(1024*4);
  int* boff       = (int*)alloc(1024*4);
  int* col        = (int*)alloc((size_t)E*4);
  float* s1       = (float*)alloc(128*4);
  float* b1c      = (float*)alloc(128*4);
  float* s2       = (float*)alloc(128*4);
  float* b2c      = (float*)alloc(128*4);
  float* atts2    = (float*)alloc(128*4);
  float* attd2    = (float*)alloc(128*4);
  float* s3       = (float*)alloc(64*4);
  float* bias3    = (float*)alloc(64*4);
  ushort16* pw_in  = (ushort16*)alloc(6*4*128*16);   // 48 KB
  ushort16* pw_gcn = (ushort16*)alloc(4*4*128*16);   // 32 KB
  ushort16* pw_gat = (ushort16*)alloc(4*4*128*16);
  ushort16* pw_cat = (ushort16*)alloc(12*4*64*16);   // 48 KB

  ushort16* h1 = xb;                 // xb dead after GEMM1
  ushort16* h3 = bufG;               // g dead after gat_gather

  // cnt and fill are adjacent allocations: one memset covers both (incl. pad)
  hipMemsetAsync(cnt, 0, (size_t)((char*)(fill + N) - (char*)cnt), stream);

  count_deg_kernel<<<(E+255)/256, 256, 0, stream>>>(dstp, E, cnt);
  scan_blocks<<<nb, 1024, 0, stream>>>(cnt, N, part, bsum);
  scan_bsum<<<1, 1024, 0, stream>>>(bsum, nb, boff, rowptr, N);
  scan_add_dinv<<<(N+255)/256, 256, 0, stream>>>(part, boff, cnt, N, rowptr, dinv);
  scatter_kernel<<<(E+255)/256, 256, 0, stream>>>(srcp, dstp, E, rowptr, fill, col);

  cvt_x<<<(N*48 + 255)/256, 256, 0, stream>>>(x, (uint2*)xb, N*48);
  prep_scales<<<1, 128, 0, stream>>>(bn1_g, bn1_b, bn1_m, bn1_v, b_gcn,
                                     bn2_g, bn2_b, bn2_m, bn2_v, b_gat,
                                     att_s, att_d,
                                     bn3_g, bn3_b, bn3_m, bn3_v, b_sage, b_res,
                                     s1, b1c, s2, b2c, atts2, attd2, s3, bias3);
  pack_all<<<320, 256, 0, stream>>>(w_in, w_gcn, w_gat, w_sl, w_sr, w_res,
                                    s1, s2, s3, pw_in, pw_gcn, pw_gat, pw_cat);

  int g128 = (N + 127)/128;
  int g256 = (N + 255)/256;
  int gagg = (N + 3)/4; if(gagg > 4096) gagg = 4096;
  int gpair = (N + 7)/8; if(gpair > 4096) gpair = 4096;

  // h = elu(x@w_in + b_in)  -> Acat[:,256:384]
  mfma_gemm<6,128,1><<<g128, 256, 0, stream>>>(xb, 192, (const uint4v*)pw_in, b_in,
      (void*)(Acat + 256), 384, N, nullptr, nullptr, nullptr, nullptr, nullptr, nullptr);
  // hw2 = (h@(w_gcn*s1))*dinv[row] -> bufG
  mfma_gemm<4,128,4><<<g128, 256, 0, stream>>>(Acat + 256, 384, (const uint4v*)pw_gcn, nullptr,
      (void*)bufG, 128, N, dinv, nullptr, nullptr, nullptr, nullptr, nullptr);
  // h1 = elu(sum(hw2)*di + b1c)   (node-pair waves)
  gcn_agg<<<gpair, 256, 0, stream>>>((const uint32*)bufG, rowptr, col, dinv, b1c,
                                     (uint32*)h1, N);
  // g' = h1@(w_gat*s2) -> bufG, + fused attention scalars / self-exp
  mfma_gemm<4,128,3><<<g128, 256, 0, stream>>>(h1, 128, (const uint4v*)pw_gat, nullptr,
      (void*)bufG, 128, N, nullptr, atts2, attd2, a_src, a_dst, ess);
  // h2 -> Acat[:,128:256]   (no-max softmax, fully in-register)
  gat_gather<<<gagg, 256, 0, stream>>>((const uint32*)bufG, rowptr, col, a_src, a_dst, ess,
                                       b2c, (uint32*)Acat + 64, N);
  // mean_nb -> Acat[:,0:128]   (node-pair waves)
  sage_mean<<<gpair, 256, 0, stream>>>((const uint32*)Acat + 64, rowptr, col, (uint32*)Acat, N);
  // h3 = elu((Acat @ [w_sl*s3; w_sr*s3; w_res]) + bias3) -> bf16
  mfma_gemm<12,64,1><<<g256, 256, 0, stream>>>(Acat, 384, (const uint4v*)pw_cat, bias3,
      (void*)h3, 64, N, nullptr, nullptr, nullptr, nullptr, nullptr, nullptr);
  classifier_kernel<<<(N+7)/8, 256, 0, stream>>>((const uint32*)h3, w_c1, b_c1, w_c2, b_c2,
                                                 (float*)d_out, N);
}

// Round 10
// 316.822 us; speedup vs baseline: 1.6374x; 1.0500x over previous
//
#include <hip/hip_runtime.h>
#include <cstdint>
#include <cstddef>

#define BN_EPS 1e-5f

typedef __attribute__((ext_vector_type(8))) short short8v;
typedef __attribute__((ext_vector_type(4))) float float4v;
typedef __attribute__((ext_vector_type(4))) unsigned int uint4v;
typedef unsigned int uint32;
typedef unsigned short ushort16;

__device__ __forceinline__ float elu_f(float v){ return v > 0.f ? v : expm1f(v); }
__device__ __forceinline__ float leaky_f(float v){ return v > 0.f ? v : 0.2f*v; }
__device__ __forceinline__ uint32 f2bf(float f){
  uint32 b = __float_as_uint(f);
  return (b + 0x7fffu + ((b >> 16) & 1u)) >> 16;        // RNE
}
__device__ __forceinline__ float bflo(uint32 u){ return __uint_as_float(u << 16); }
__device__ __forceinline__ float bfhi(uint32 u){ return __uint_as_float(u & 0xffff0000u); }
__device__ __forceinline__ float readlane_f(float v, int l){
  return __int_as_float(__builtin_amdgcn_readlane(__float_as_int(v), l));
}

// ---------------- graph preprocessing: CSR by dst ----------------

__global__ void count_deg_kernel(const int* __restrict__ dst, int E, int* __restrict__ cnt){
  int i = blockIdx.x*blockDim.x + threadIdx.x;
  if(i < E) atomicAdd(&cnt[dst[i]], 1);
}

__global__ __launch_bounds__(1024) void scan_blocks(const int* __restrict__ cnt, int n,
                                                    int* __restrict__ part, int* __restrict__ bsum){
  __shared__ int wsum[16];
  int tid = threadIdx.x, lane = tid & 63, w = tid >> 6;
  int i = blockIdx.x*1024 + tid;
  int v = (i < n) ? cnt[i] : 0;
  int sv = v;
#pragma unroll
  for(int o = 1; o < 64; o <<= 1){
    int u = __shfl_up(sv, o);
    if(lane >= o) sv += u;
  }
  if(lane == 63) wsum[w] = sv;
  __syncthreads();
  int woff = 0;
#pragma unroll
  for(int q = 0; q < 16; q++) woff += (q < w) ? wsum[q] : 0;
  if(i < n) part[i] = woff + sv - v;
  if(tid == 1023) bsum[blockIdx.x] = woff + sv;
}

__global__ __launch_bounds__(1024) void scan_bsum(const int* __restrict__ bsum, int nb,
                                                  int* __restrict__ boff, int* __restrict__ rowptr, int n){
  __shared__ int wsum[16];
  int tid = threadIdx.x, lane = tid & 63, w = tid >> 6;
  int v = (tid < nb) ? bsum[tid] : 0;
  int sv = v;
#pragma unroll
  for(int o = 1; o < 64; o <<= 1){
    int u = __shfl_up(sv, o);
    if(lane >= o) sv += u;
  }
  if(lane == 63) wsum[w] = sv;
  __syncthreads();
  int woff = 0;
#pragma unroll
  for(int q = 0; q < 16; q++) woff += (q < w) ? wsum[q] : 0;
  if(tid < nb) boff[tid] = woff + sv - v;
  if(tid == 1023) rowptr[n] = woff + sv;
}

__global__ void scan_add_dinv(const int* __restrict__ part, const int* __restrict__ boff,
                              const int* __restrict__ cnt, int n,
                              int* __restrict__ rowptr, float* __restrict__ dinv){
  int i = blockIdx.x*blockDim.x + threadIdx.x;
  if(i < n){
    rowptr[i] = part[i] + boff[i >> 10];
    dinv[i] = rsqrtf((float)cnt[i] + 1.0f);   // deg includes self loop
  }
}

__global__ void scatter_kernel(const int* __restrict__ src, const int* __restrict__ dst, int E,
                               const int* __restrict__ rowptr, int* __restrict__ fill,
                               int* __restrict__ col){
  int i = blockIdx.x*blockDim.x + threadIdx.x;
  if(i < E){
    int s = src[i], d = dst[i];
    int p = rowptr[d] + atomicAdd(&fill[d], 1);
    col[p] = s;
  }
}

// ---------------- x -> bf16, K padded 165 -> 192, uint2 writes ----------------

__global__ __launch_bounds__(256) void cvt_x(const float* __restrict__ x, uint2* __restrict__ xb, int total){
  int idx = blockIdx.x*256 + threadIdx.x;     // over N*48 uint2
  if(idx >= total) return;
  int row = idx/48;
  int cp = idx - row*48;
  int c = cp*4;
  const float* xr = x + (size_t)row*165;
  float v0 = (c   < 165) ? xr[c]   : 0.f;
  float v1 = (c+1 < 165) ? xr[c+1] : 0.f;
  float v2 = (c+2 < 165) ? xr[c+2] : 0.f;
  float v3 = (c+3 < 165) ? xr[c+3] : 0.f;
  xb[idx] = make_uint2(f2bf(v0) | (f2bf(v1) << 16), f2bf(v2) | (f2bf(v3) << 16));
}

// ---------------- BN folding: per-channel scales + combined biases ----------------

__global__ void prep_scales(const float* __restrict__ bn1_g, const float* __restrict__ bn1_b,
    const float* __restrict__ bn1_m, const float* __restrict__ bn1_v, const float* __restrict__ b_gcn,
    const float* __restrict__ bn2_g, const float* __restrict__ bn2_b,
    const float* __restrict__ bn2_m, const float* __restrict__ bn2_v, const float* __restrict__ b_gat,
    const float* __restrict__ att_s, const float* __restrict__ att_d,
    const float* __restrict__ bn3_g, const float* __restrict__ bn3_b,
    const float* __restrict__ bn3_m, const float* __restrict__ bn3_v,
    const float* __restrict__ b_sage, const float* __restrict__ b_res,
    float* __restrict__ s1, float* __restrict__ b1c,
    float* __restrict__ s2, float* __restrict__ b2c,
    float* __restrict__ atts2, float* __restrict__ attd2,
    float* __restrict__ s3, float* __restrict__ bias3){
  int c = threadIdx.x;   // 128
  float v1 = bn1_g[c]*rsqrtf(bn1_v[c] + BN_EPS);
  s1[c] = v1;
  b1c[c] = (b_gcn[c] - bn1_m[c])*v1 + bn1_b[c];
  float v2 = bn2_g[c]*rsqrtf(bn2_v[c] + BN_EPS);
  s2[c] = v2;
  b2c[c] = (b_gat[c] - bn2_m[c])*v2 + bn2_b[c];
  atts2[c] = att_s[c]/v2;
  attd2[c] = att_d[c]/v2;
  if(c < 64){
    float v3 = bn3_g[c]*rsqrtf(bn3_v[c] + BN_EPS);
    s3[c] = v3;
    bias3[c] = (b_sage[c] - bn3_m[c])*v3 + bn3_b[c] + b_res[c];
  }
}

// ---------------- weight packing (one launch): packed[kgrp][col][8] bf16 ----------------

__device__ __forceinline__ void pack_region(const float* __restrict__ W, int K, int NOUT, int kbase, int idx,
                                            const float* __restrict__ scale, ushort16* __restrict__ out){
  int k = idx / NOUT, c = idx - k*NOUT;
  float v = (k < K) ? W[(size_t)k*NOUT + c] : 0.f;
  if(scale) v *= scale[c];
  int pk = kbase + k;
  out[(size_t)(pk >> 3)*NOUT*8 + (size_t)c*8 + (pk & 7)] = (ushort16)f2bf(v);
}

__global__ __launch_bounds__(256) void pack_all(const float* __restrict__ w_in, const float* __restrict__ w_gcn,
    const float* __restrict__ w_gat, const float* __restrict__ w_sl, const float* __restrict__ w_sr,
    const float* __restrict__ w_res,
    const float* __restrict__ s1, const float* __restrict__ s2, const float* __restrict__ s3,
    ushort16* __restrict__ pw_in, ushort16* __restrict__ pw_gcn,
    ushort16* __restrict__ pw_gat, ushort16* __restrict__ pw_cat){
  int b = blockIdx.x, t = threadIdx.x;
  if(b < 96)       pack_region(w_in,  165, 128, 0,   b*256 + t,        nullptr, pw_in);
  else if(b < 160) pack_region(w_gcn, 128, 128, 0,   (b-96)*256 + t,   s1,      pw_gcn);
  else if(b < 224) pack_region(w_gat, 128, 128, 0,   (b-160)*256 + t,  s2,      pw_gat);
  else if(b < 256) pack_region(w_sl,  128, 64,  0,   (b-224)*256 + t,  s3,      pw_cat);
  else if(b < 288) pack_region(w_sr,  128, 64,  128, (b-256)*256 + t,  s3,      pw_cat);
  else             pack_region(w_res, 128, 64,  256, (b-288)*256 + t,  nullptr, pw_cat);
}

// ---------------- MFMA bf16 GEMM ----------------
// Swapped-operand form: acc = mfma(Wfrag, Afrag) -> lane holds one output ROW,
// regs hold 4 consecutive output cols -> 8B uint2 stores.
// Per-K-step double-buffered W staging in LDS (16KB / 8KB) for occupancy.
// EPI: 0 raw->bf16, 1 bias+elu->bf16, 3 raw->bf16 + fused GAT attention epilogue,
//      4 row-scale by dinv[r] -> bf16 (GCN fold)

template<int KSTEPS, int NOUT, int EPI>
__global__ __launch_bounds__(256) void mfma_gemm(
    const ushort16* __restrict__ A, int lda,
    const uint4v* __restrict__ pw,
    const float* __restrict__ bias,
    void* __restrict__ out, int ldo, int N,
    const float* __restrict__ dinv,
    const float* __restrict__ atts2, const float* __restrict__ attd2,
    float* __restrict__ a_src, float* __restrict__ a_dst,
    float* __restrict__ ess)
{
  constexpr int SLICE = 4*NOUT;          // uint4 per K-step W slice
  constexpr int PT = SLICE/256;          // uint4 per thread per slice (2 or 1)
  __shared__ uint4v wlds[2][SLICE];
  int t = threadIdx.x;
  int wid = t >> 6, lane = t & 63;
  int wm, wn;
  if(NOUT == 128){ wm = wid >> 1; wn = wid & 1; } else { wm = wid; wn = 0; }
  constexpr int MTILE = (NOUT == 128) ? 128 : 256;
  long row0 = (long)blockIdx.x*MTILE + wm*64;
  int l15 = lane & 15, lk = lane >> 4;
  int wn64 = wn*64;

  float4v acc[4][4];
#pragma unroll
  for(int fm = 0; fm < 4; fm++)
#pragma unroll
    for(int fn = 0; fn < 4; fn++) acc[fm][fn] = (float4v){0.f,0.f,0.f,0.f};

  const ushort16* abase[4];
#pragma unroll
  for(int fm = 0; fm < 4; fm++){
    long r = row0 + fm*16 + l15;
    if(r > (long)N - 1) r = (long)N - 1;
    abase[fm] = A + r*(size_t)lda + lk*8;
  }

  // stage slice 0 -> buf0; prefetch slice 1 -> regs; load first A fragments
  uint4v rst[PT];
#pragma unroll
  for(int i = 0; i < PT; i++) rst[i] = pw[i*256 + t];
#pragma unroll
  for(int i = 0; i < PT; i++) wlds[0][i*256 + t] = rst[i];
  if(KSTEPS > 1){
#pragma unroll
    for(int i = 0; i < PT; i++) rst[i] = pw[SLICE + i*256 + t];
  }
  short8v a[4];
#pragma unroll
  for(int fm = 0; fm < 4; fm++) a[fm] = *(const short8v*)(abase[fm]);
  __syncthreads();

#pragma unroll
  for(int ks = 0; ks < KSTEPS; ks++){
    short8v b[4];
#pragma unroll
    for(int fn = 0; fn < 4; fn++)
      b[fn] = *(const short8v*)&wlds[ks & 1][lk*NOUT + wn64 + fn*16 + l15];
    short8v an[4];
    if(ks + 1 < KSTEPS){
#pragma unroll
      for(int fm = 0; fm < 4; fm++) an[fm] = *(const short8v*)(abase[fm] + (ks + 1)*32);
    }
#pragma unroll
    for(int fm = 0; fm < 4; fm++)
#pragma unroll
      for(int fn = 0; fn < 4; fn++)
        acc[fm][fn] = __builtin_amdgcn_mfma_f32_16x16x32_bf16(b[fn], a[fm], acc[fm][fn], 0, 0, 0);
    if(ks + 1 < KSTEPS){
#pragma unroll
      for(int i = 0; i < PT; i++) wlds[(ks + 1) & 1][i*256 + t] = rst[i];
      if(ks + 2 < KSTEPS){
#pragma unroll
        for(int i = 0; i < PT; i++) rst[i] = pw[(size_t)(ks + 2)*SLICE + i*256 + t];
      }
#pragma unroll
      for(int fm = 0; fm < 4; fm++) a[fm] = an[fm];
    }
    __syncthreads();
  }

  // Swapped C/D layout: lane l15 -> output row, (lk*4 + reg) within fn-block -> cols
#pragma unroll
  for(int fm = 0; fm < 4; fm++){
    long r = row0 + fm*16 + l15;
    if(r < N){
      float dr = 0.f;
      if constexpr(EPI == 4) dr = dinv[r];
#pragma unroll
      for(int fn = 0; fn < 4; fn++){
        int c0 = wn64 + fn*16 + lk*4;
        float v0 = acc[fm][fn][0], v1 = acc[fm][fn][1];
        float v2 = acc[fm][fn][2], v3 = acc[fm][fn][3];
        if constexpr(EPI == 1){
          float4 bs = *(const float4*)(bias + c0);
          v0 = elu_f(v0 + bs.x); v1 = elu_f(v1 + bs.y);
          v2 = elu_f(v2 + bs.z); v3 = elu_f(v3 + bs.w);
        }
        if constexpr(EPI == 4){ v0 *= dr; v1 *= dr; v2 *= dr; v3 *= dr; }
        uint2 ov = make_uint2(f2bf(v0) | (f2bf(v1) << 16), f2bf(v2) | (f2bf(v3) << 16));
        *(uint2*)((ushort16*)out + r*(size_t)ldo + c0) = ov;
      }
    }
  }

  if constexpr(EPI == 3){
    // fused GAT attention scalars: wn selects head; lane holds 16 of 64 head-cols of row r
    float4 asv[4], adv[4];
#pragma unroll
    for(int fn = 0; fn < 4; fn++){
      int c0 = wn64 + fn*16 + lk*4;
      asv[fn] = *(const float4*)(atts2 + c0);
      adv[fn] = *(const float4*)(attd2 + c0);
    }
#pragma unroll
    for(int fm = 0; fm < 4; fm++){
      float p1 = 0.f, p2 = 0.f;
#pragma unroll
      for(int fn = 0; fn < 4; fn++){
        p1 += acc[fm][fn][0]*asv[fn].x + acc[fm][fn][1]*asv[fn].y
            + acc[fm][fn][2]*asv[fn].z + acc[fm][fn][3]*asv[fn].w;
        p2 += acc[fm][fn][0]*adv[fn].x + acc[fm][fn][1]*adv[fn].y
            + acc[fm][fn][2]*adv[fn].z + acc[fm][fn][3]*adv[fn].w;
      }
      p1 += __shfl_xor(p1, 16); p1 += __shfl_xor(p1, 32);
      p2 += __shfl_xor(p2, 16); p2 += __shfl_xor(p2, 32);
      long r = row0 + fm*16 + l15;
      if(lane < 16 && r < N){
        a_src[2*r + wn] = p1;
        a_dst[2*r + wn] = p2;
        ess[2*r + wn] = __expf(leaky_f(p1 + p2));   // self-exp, M=0 (exact: M cancels)
      }
    }
  }
}

// ---------------- GCN aggregation (dinv pre-folded) + BN1 + ELU ----------------
// node-pair per wave: 2 interleaved gather streams double in-flight loads

__global__ __launch_bounds__(256) void gcn_agg(const uint32* __restrict__ hw2,   // stride 64 uints
    const int* __restrict__ rowptr, const int* __restrict__ col,
    const float* __restrict__ dinv, const float* __restrict__ b1c,
    uint32* __restrict__ h1, int N)
{
  int t = threadIdx.x & 63;
  int w = __builtin_amdgcn_readfirstlane(threadIdx.x >> 6);
  float2 bc = ((const float2*)b1c)[t];
  int stride = gridDim.x*8;
  for(int i0 = (blockIdx.x*4 + w)*2; i0 < N; i0 += stride){
    int i1 = i0 + 1;
    bool has1 = i1 < N;
    int beg0 = rowptr[i0];
    int end0 = rowptr[i0+1];
    int beg1 = end0;                       // rowptr[i1] == end0 (consecutive nodes)
    int end1 = has1 ? rowptr[i1+1] : end0;
    float di0 = dinv[i0];
    float di1 = has1 ? dinv[i1] : 0.f;
    uint32 su0 = hw2[(size_t)i0*64 + t];
    float a00 = bflo(su0), a01 = bfhi(su0);   // self loop (dinv folded into hw2)
    float a10 = 0.f, a11 = 0.f;
    if(has1){ uint32 su1 = hw2[(size_t)i1*64 + t]; a10 = bflo(su1); a11 = bfhi(su1); }
#define R0(q) { int row = __builtin_amdgcn_readlane(s0, q); \
    uint32 u = hw2[(size_t)row*64 + t]; a00 += bflo(u); a01 += bfhi(u); }
#define R1(q) { int row = __builtin_amdgcn_readlane(s1, q); \
    uint32 u = hw2[(size_t)row*64 + t]; a10 += bflo(u); a11 += bfhi(u); }
    for(int c0 = beg0, c1 = beg1; c0 < end0 || c1 < end1; c0 += 64, c1 += 64){
      int p0 = c0 + t, p1 = c1 + t;
      int s0 = (p0 < end0) ? col[p0] : 0;
      int s1 = (p1 < end1) ? col[p1] : 0;
      int cl0 = end0 - c0; cl0 = cl0 < 0 ? 0 : (cl0 > 64 ? 64 : cl0);
      int cl1 = end1 - c1; cl1 = cl1 < 0 ? 0 : (cl1 > 64 ? 64 : cl1);
      int m = cl0 < cl1 ? cl0 : cl1;
      int q = 0;
      for(; q + 2 <= m; q += 2){ R0(q) R1(q) R0(q+1) R1(q+1) }
      for(; q < m; q++){ R0(q) R1(q) }
      for(int qa = m; qa < cl0; qa++){ R0(qa) }
      for(int qb = m; qb < cl1; qb++){ R1(qb) }
    }
#undef R0
#undef R1
    h1[(size_t)i0*64 + t] = f2bf(elu_f(a00*di0 + bc.x)) | (f2bf(elu_f(a01*di0 + bc.y)) << 16);
    if(has1)
      h1[(size_t)i1*64 + t] = f2bf(elu_f(a10*di1 + bc.x)) | (f2bf(elu_f(a11*di1 + bc.y)) << 16);
  }
}

// ---------------- GAT gather: no-max softmax (exact) + weighted sum + BN2 + ELU ----------
// writes h2 (bf16) into Acat[:,128:256]  (out pre-offset, stride 192 uints)

__global__ __launch_bounds__(256) void gat_gather(const uint32* __restrict__ g,   // stride 64
    const int* __restrict__ rowptr, const int* __restrict__ col,
    const float* __restrict__ a_src, const float* __restrict__ a_dst,
    const float* __restrict__ ess, const float* __restrict__ b2c,
    uint32* __restrict__ h2out, int N)
{
  int t = threadIdx.x & 63;
  int w = __builtin_amdgcn_readfirstlane(threadIdx.x >> 6);
  float2 bc = ((const float2*)b2c)[t];
  int hl = t >> 5;
  int stride = gridDim.x*4;
  for(int i = blockIdx.x*4 + w; i < N; i += stride){
    int beg = rowptr[i], end = rowptr[i+1];
    int deg = end - beg;
    float2 ad = ((const float2*)a_dst)[i];
    float sw0 = ess[2*i], sw1 = ess[2*i+1];    // exp(self logit), M=0
    float d0 = 0.f, d1 = 0.f, a0 = 0.f, a1 = 0.f;
#define GAT_ROWF(q) { int row = __builtin_amdgcn_readlane(s, q); \
    float w0q = readlane_f(e0, q); \
    float w1q = readlane_f(e1, q); \
    float wq = hl ? w1q : w0q; \
    uint32 u = g[(size_t)row*64 + t]; a0 += wq*bflo(u); a1 += wq*bfhi(u); }
    if(deg <= 64){
      int p = beg + t;
      int s = 0; float e0 = 0.f, e1 = 0.f;
      if(p < end){
        s = col[p];
        float2 as = ((const float2*)a_src)[s];
        e0 = __expf(leaky_f(as.x + ad.x));
        e1 = __expf(leaky_f(as.y + ad.y));
      }
      d0 = e0; d1 = e1;
      int q = 0;
      for(; q + 4 <= deg; q += 4){ GAT_ROWF(q) GAT_ROWF(q+1) GAT_ROWF(q+2) GAT_ROWF(q+3) }
      for(; q < deg; q++){ GAT_ROWF(q) }
    } else {
      for(int c0 = beg; c0 < end; c0 += 64){
        int p = c0 + t;
        int cl = end - c0; if(cl > 64) cl = 64;
        float e0 = 0.f, e1 = 0.f; int s = 0;
        if(p < end){
          s = col[p];
          float2 as = ((const float2*)a_src)[s];
          e0 = __expf(leaky_f(as.x + ad.x));
          e1 = __expf(leaky_f(as.y + ad.y));
        }
        d0 += e0; d1 += e1;
        int q = 0;
        for(; q + 4 <= cl; q += 4){ GAT_ROWF(q) GAT_ROWF(q+1) GAT_ROWF(q+2) GAT_ROWF(q+3) }
        for(; q < cl; q++){ GAT_ROWF(q) }
      }
    }
#undef GAT_ROWF
#pragma unroll
    for(int o = 32; o > 0; o >>= 1){ d0 += __shfl_xor(d0, o); d1 += __shfl_xor(d1, o); }
    float rD = 1.f/(((hl ? d1 : d0) + (hl ? sw1 : sw0)) + 1e-16f);
    float sw = hl ? sw1 : sw0;
    uint32 su = g[(size_t)i*64 + t];
    float v0 = (a0 + sw*bflo(su))*rD + bc.x;
    float v1 = (a1 + sw*bfhi(su))*rD + bc.y;
    h2out[(size_t)i*192 + t] = f2bf(elu_f(v0)) | (f2bf(elu_f(v1)) << 16);
  }
}

// ---------------- SAGE mean (no self loops), node-pair per wave, inside Acat ----------------

__global__ __launch_bounds__(256) void sage_mean(const uint32* __restrict__ h2,  // pre-offset +64, stride 192
    const int* __restrict__ rowptr, const int* __restrict__ col,
    uint32* __restrict__ mout, int N)                                             // stride 192
{
  int t = threadIdx.x & 63;
  int w = __builtin_amdgcn_readfirstlane(threadIdx.x >> 6);
  int stride = gridDim.x*8;
  for(int i0 = (blockIdx.x*4 + w)*2; i0 < N; i0 += stride){
    int i1 = i0 + 1;
    bool has1 = i1 < N;
    int beg0 = rowptr[i0];
    int end0 = rowptr[i0+1];
    int beg1 = end0;
    int end1 = has1 ? rowptr[i1+1] : end0;
    float a00 = 0.f, a01 = 0.f, a10 = 0.f, a11 = 0.f;
#define S0(q) { int row = __builtin_amdgcn_readlane(s0, q); \
    uint32 u = h2[(size_t)row*192 + t]; a00 += bflo(u); a01 += bfhi(u); }
#define S1(q) { int row = __builtin_amdgcn_readlane(s1, q); \
    uint32 u = h2[(size_t)row*192 + t]; a10 += bflo(u); a11 += bfhi(u); }
    for(int c0 = beg0, c1 = beg1; c0 < end0 || c1 < end1; c0 += 64, c1 += 64){
      int p0 = c0 + t, p1 = c1 + t;
      int s0 = (p0 < end0) ? col[p0] : 0;
      int s1 = (p1 < end1) ? col[p1] : 0;
      int cl0 = end0 - c0; cl0 = cl0 < 0 ? 0 : (cl0 > 64 ? 64 : cl0);
      int cl1 = end1 - c1; cl1 = cl1 < 0 ? 0 : (cl1 > 64 ? 64 : cl1);
      int m = cl0 < cl1 ? cl0 : cl1;
      int q = 0;
      for(; q + 2 <= m; q += 2){ S0(q) S1(q) S0(q+1) S1(q+1) }
      for(; q < m; q++){ S0(q) S1(q) }
      for(int qa = m; qa < cl0; qa++){ S0(qa) }
      for(int qb = m; qb < cl1; qb++){ S1(qb) }
    }
#undef S0
#undef S1
    float inv0 = 1.f/fmaxf((float)(end0 - beg0), 1.f);
    mout[(size_t)i0*192 + t] = f2bf(a00*inv0) | (f2bf(a01*inv0) << 16);
    if(has1){
      float inv1 = 1.f/fmaxf((float)(end1 - beg1), 1.f);
      mout[(size_t)i1*192 + t] = f2bf(a10*inv1) | (f2bf(a11*inv1) << 16);
    }
  }
}

// ---------------- classifier: out = elu(h3@w1+b1)@w2 + b2  (h3 bf16) ----------------

__global__ __launch_bounds__(256) void classifier_kernel(const uint32* __restrict__ h3,  // stride 32 uints
    const float* __restrict__ w1, const float* __restrict__ b1,
    const float* __restrict__ w2, const float* __restrict__ b2,
    float* __restrict__ out, int N)
{
  __shared__ float hs[8][64];
  __shared__ float zs[8][32];
  int node0 = blockIdx.x*8;
  int t = threadIdx.x;
  {
    int r = t >> 5, cp = t & 31;
    int nd = node0 + r;
    uint32 u = (nd < N) ? h3[(size_t)nd*32 + cp] : 0u;
    hs[r][2*cp]   = bflo(u);
    hs[r][2*cp+1] = bfhi(u);
  }
  __syncthreads();
  int nn = t >> 5, ln = t & 31;
  float acc = b1[ln];
#pragma unroll
  for(int k = 0; k < 64; k++) acc += hs[nn][k]*w1[k*32 + ln];
  zs[nn][ln] = elu_f(acc);
  __syncthreads();
  int node = node0 + nn;
  if(ln < 2 && node < N){
    float o = b2[ln];
#pragma unroll
    for(int k = 0; k < 32; k++) o += zs[nn][k]*w2[k*2 + ln];
    out[(size_t)node*2 + ln] = o;
  }
}

// ---------------- launch ----------------

extern "C" void kernel_launch(void* const* d_in, const int* in_sizes, int n_in,
                              void* d_out, int out_size, void* d_ws, size_t ws_size,
                              hipStream_t stream)
{
  (void)n_in; (void)out_size; (void)ws_size;
  const float* x      = (const float*)d_in[0];
  const int*   ei     = (const int*)  d_in[1];
  const float* w_in   = (const float*)d_in[2];
  const float* b_in   = (const float*)d_in[3];
  const float* w_gcn  = (const float*)d_in[4];
  const float* b_gcn  = (const float*)d_in[5];
  const float* bn1_g  = (const float*)d_in[6];
  const float* bn1_b  = (const float*)d_in[7];
  const float* bn1_m  = (const float*)d_in[8];
  const float* bn1_v  = (const float*)d_in[9];
  const float* w_gat  = (const float*)d_in[10];
  const float* att_s  = (const float*)d_in[11];
  const float* att_d  = (const float*)d_in[12];
  const float* b_gat  = (const float*)d_in[13];
  const float* bn2_g  = (const float*)d_in[14];
  const float* bn2_b  = (const float*)d_in[15];
  const float* bn2_m  = (const float*)d_in[16];
  const float* bn2_v  = (const float*)d_in[17];
  const float* w_sl   = (const float*)d_in[18];
  const float* b_sage = (const float*)d_in[19];
  const float* w_sr   = (const float*)d_in[20];
  const float* bn3_g  = (const float*)d_in[21];
  const float* bn3_b  = (const float*)d_in[22];
  const float* bn3_m  = (const float*)d_in[23];
  const float* bn3_v  = (const float*)d_in[24];
  const float* w_res  = (const float*)d_in[25];
  const float* b_res  = (const float*)d_in[26];
  const float* w_c1   = (const float*)d_in[27];
  const float* b_c1   = (const float*)d_in[28];
  const float* w_c2   = (const float*)d_in[29];
  const float* b_c2   = (const float*)d_in[30];

  const int F_IN = 165;
  int N = in_sizes[0]/F_IN;
  int E = in_sizes[1]/2;
  const int* srcp = ei;
  const int* dstp = ei + E;
  int nb = (N + 1023) >> 10;

  char* p = (char*)d_ws;
  auto alloc = [&](size_t bytes) -> char* {
    char* q = p; p += (bytes + 255) & ~(size_t)255; return q;
  };
  ushort16* Acat  = (ushort16*)alloc((size_t)N*384*2);   // [mean_nb | h2 | h]
  ushort16* xb    = (ushort16*)alloc((size_t)N*192*2);   // later reused for h1
  ushort16* bufG  = (ushort16*)alloc((size_t)N*128*2);   // hw2 -> g -> h3(bf16)
  float* a_src    = (float*)alloc((size_t)N*2*4);
  float* a_dst    = (float*)alloc((size_t)N*2*4);
  float* ess      = (float*)alloc((size_t)N*2*4);
  float* dinv     = (float*)alloc((size_t)N*4);
  int* cnt        = (int*)alloc((size_t)N*4);
  int* fill       = (int*)alloc((size_t)N*4);
  int* rowptr     = (int*)alloc((size_t)(N+1)*4);
  int* part       = (int*)alloc((size_t)N*4);
  int* bsum       = (int*)alloc(1024*4);
  int* boff       = (int*)alloc(1024*4);
  int* col        = (int*)alloc((size_t)E*4);
  float* s1       = (float*)alloc(128*4);
  float* b1c      = (float*)alloc(128*4);
  float* s2       = (float*)alloc(128*4);
  float* b2c      = (float*)alloc(128*4);
  float* atts2    = (float*)alloc(128*4);
  float* attd2    = (float*)alloc(128*4);
  float* s3       = (float*)alloc(64*4);
  float* bias3    = (float*)alloc(64*4);
  ushort16* pw_in  = (ushort16*)alloc(6*4*128*16);   // 48 KB
  ushort16* pw_gcn = (ushort16*)alloc(4*4*128*16);   // 32 KB
  ushort16* pw_gat = (ushort16*)alloc(4*4*128*16);
  ushort16* pw_cat = (ushort16*)alloc(12*4*64*16);   // 48 KB

  ushort16* h1 = xb;                 // xb dead after GEMM1
  ushort16* h3 = bufG;               // g dead after gat_gather

  // cnt and fill are adjacent allocations: one memset covers both (incl. pad)
  hipMemsetAsync(cnt, 0, (size_t)((char*)(fill + N) - (char*)cnt), stream);

  count_deg_kernel<<<(E+255)/256, 256, 0, stream>>>(dstp, E, cnt);
  scan_blocks<<<nb, 1024, 0, stream>>>(cnt, N, part, bsum);
  scan_bsum<<<1, 1024, 0, stream>>>(bsum, nb, boff, rowptr, N);
  scan_add_dinv<<<(N+255)/256, 256, 0, stream>>>(part, boff, cnt, N, rowptr, dinv);
  scatter_kernel<<<(E+255)/256, 256, 0, stream>>>(srcp, dstp, E, rowptr, fill, col);

  cvt_x<<<(N*48 + 255)/256, 256, 0, stream>>>(x, (uint2*)xb, N*48);
  prep_scales<<<1, 128, 0, stream>>>(bn1_g, bn1_b, bn1_m, bn1_v, b_gcn,
                                     bn2_g, bn2_b, bn2_m, bn2_v, b_gat,
                                     att_s, att_d,
                                     bn3_g, bn3_b, bn3_m, bn3_v, b_sage, b_res,
                                     s1, b1c, s2, b2c, atts2, attd2, s3, bias3);
  pack_all<<<320, 256, 0, stream>>>(w_in, w_gcn, w_gat, w_sl, w_sr, w_res,
                                    s1, s2, s3, pw_in, pw_gcn, pw_gat, pw_cat);

  int g128 = (N + 127)/128;
  int g256 = (N + 255)/256;
  int gagg = (N + 3)/4; if(gagg > 4096) gagg = 4096;
  int gpair = (N + 7)/8; if(gpair > 4096) gpair = 4096;

  // h = elu(x@w_in + b_in)  -> Acat[:,256:384]
  mfma_gemm<6,128,1><<<g128, 256, 0, stream>>>(xb, 192, (const uint4v*)pw_in, b_in,
      (void*)(Acat + 256), 384, N, nullptr, nullptr, nullptr, nullptr, nullptr, nullptr);
  // hw2 = (h@(w_gcn*s1))*dinv[row] -> bufG
  mfma_gemm<4,128,4><<<g128, 256, 0, stream>>>(Acat + 256, 384, (const uint4v*)pw_gcn, nullptr,
      (void*)bufG, 128, N, dinv, nullptr, nullptr, nullptr, nullptr, nullptr);
  // h1 = elu(sum(hw2)*di + b1c)   (node-pair waves)
  gcn_agg<<<gpair, 256, 0, stream>>>((const uint32*)bufG, rowptr, col, dinv, b1c,
                                     (uint32*)h1, N);
  // g' = h1@(w_gat*s2) -> bufG, + fused attention scalars / self-exp
  mfma_gemm<4,128,3><<<g128, 256, 0, stream>>>(h1, 128, (const uint4v*)pw_gat, nullptr,
      (void*)bufG, 128, N, nullptr, atts2, attd2, a_src, a_dst, ess);
  // h2 -> Acat[:,128:256]   (no-max softmax, fully in-register)
  gat_gather<<<gagg, 256, 0, stream>>>((const uint32*)bufG, rowptr, col, a_src, a_dst, ess,
                                       b2c, (uint32*)Acat + 64, N);
  // mean_nb -> Acat[:,0:128]   (node-pair waves)
  sage_mean<<<gpair, 256, 0, stream>>>((const uint32*)Acat + 64, rowptr, col, (uint32*)Acat, N);
  // h3 = elu((Acat @ [w_sl*s3; w_sr*s3; w_res]) + bias3) -> bf16
  mfma_gemm<12,64,1><<<g256, 256, 0, stream>>>(Acat, 384, (const uint4v*)pw_cat, bias3,
      (void*)h3, 64, N, nullptr, nullptr, nullptr, nullptr, nullptr, nullptr);
  classifier_kernel<<<(N+7)/8, 256, 0, stream>>>((const uint32*)h3, w_c1, b_c1, w_c2, b_c2,
                                                 (float*)d_out, N);
}